// Round 25
// baseline (224.890 us; speedup 1.0000x reference)
//
#include <hip/hip_runtime.h>

typedef unsigned short u16;
typedef unsigned int u32;
typedef __attribute__((ext_vector_type(8))) __bf16 bf16x8;
typedef __attribute__((ext_vector_type(8))) u16 u16x8;
typedef __attribute__((ext_vector_type(4))) u16 u16x4;
typedef __attribute__((ext_vector_type(4))) float f32x4;

#define B_ 2
#define S_ 2048
#define H_ 2048
#define NH_ 16
#define NKV_ 4
#define HD_ 128
#define QSCALE 0.1275179064f  // log2(e)/sqrt(128) -> log2-domain scores

__device__ __forceinline__ u16 f2bf(float f) {
  return __builtin_bit_cast(u16, static_cast<__bf16>(f));
}
__device__ __forceinline__ float bf2f(u16 v) {
  return __builtin_bit_cast(float, (u32)v << 16);
}
__device__ __forceinline__ void gl2lds16(const void* g, void* l) {
  __builtin_amdgcn_global_load_lds((const __attribute__((address_space(1))) u32*)g,
                                   (__attribute__((address_space(3))) u32*)l, 16, 0, 0);
}
__device__ __forceinline__ f32x4 mfma16(bf16x8 a, bf16x8 b, f32x4 c) {
  return __builtin_amdgcn_mfma_f32_16x16x32_bf16(a, b, c, 0, 0, 0);
}

// ---------------- fp32 -> bf16 convert (vectorized) ----------------
__global__ __launch_bounds__(256) void cvt_f32_bf16(const float* __restrict__ in,
                                                    u16* __restrict__ out) {
  size_t i = ((size_t)blockIdx.x * 256 + threadIdx.x) * 8;
  const float4* p = (const float4*)(in + i);
  float4 a = p[0], b = p[1];
  u16x8 o;
  o[0] = f2bf(a.x); o[1] = f2bf(a.y); o[2] = f2bf(a.z); o[3] = f2bf(a.w);
  o[4] = f2bf(b.x); o[5] = f2bf(b.y); o[6] = f2bf(b.z); o[7] = f2bf(b.w);
  *(u16x8*)(out + i) = o;
}

// ---------------- fused weight transpose: wq|wk|wv (f32) -> wqkvT (bf16) ----
__global__ __launch_bounds__(256) void transpose_qkv(const float* __restrict__ wq,
                                                     const float* __restrict__ wk,
                                                     const float* __restrict__ wv,
                                                     u16* __restrict__ out) {
  __shared__ float tl[32][33];
  int bx = blockIdx.x, by = blockIdx.y;
  int tx = threadIdx.x & 31, ty = threadIdx.x >> 5;
  int orow0 = bx * 32;
  const float* src;
  int scol0, C;
  if (orow0 < 2048)      { src = wq; scol0 = orow0;        C = 2048; }
  else if (orow0 < 2560) { src = wk; scol0 = orow0 - 2048; C = 512; }
  else                   { src = wv; scol0 = orow0 - 2560; C = 512; }
#pragma unroll
  for (int i = 0; i < 32; i += 8)
    tl[ty + i][tx] = src[(size_t)(by * 32 + ty + i) * C + scol0 + tx];
  __syncthreads();
#pragma unroll
  for (int i = 0; i < 32; i += 8)
    out[(size_t)(orow0 + ty + i) * 2048 + by * 32 + tx] = f2bf(tl[tx][ty + i]);
}

// ---------------- transpose fp32 [R][C] -> bf16 [C][R] ----------------
__global__ __launch_bounds__(256) void transpose_f32_bf16(const float* __restrict__ in,
                                                          u16* __restrict__ out,
                                                          int R, int C) {
  __shared__ float tl[32][33];
  int bx = blockIdx.x, by = blockIdx.y;
  int tx = threadIdx.x & 31, ty = threadIdx.x >> 5;
#pragma unroll
  for (int i = 0; i < 32; i += 8)
    tl[ty + i][tx] = in[(size_t)(by * 32 + ty + i) * C + bx * 32 + tx];
  __syncthreads();
#pragma unroll
  for (int i = 0; i < 32; i += 8)
    out[(size_t)(bx * 32 + ty + i) * R + by * 32 + tx] = f2bf(tl[tx][ty + i]);
}

// ---------------- RoPE cos/sin table: tab[s][i] = {cos,sin}(s * 10000^(-i/64))
__global__ __launch_bounds__(256) void rope_table(float* __restrict__ tab) {
  int idx = blockIdx.x * 256 + threadIdx.x;  // 131072 = 2048 x 64
  int s = idx >> 6, i = idx & 63;
  float inv = exp2f((float)i * -0.20762050593045702f);
  float ang = (float)s * inv;
  tab[2 * idx] = cosf(ang);
  tab[2 * idx + 1] = sinf(ang);
}

// ---------------- RoPE in place on bf16 buffer (table-driven; K only) --------
__global__ __launch_bounds__(256) void rope_kernel(u16* __restrict__ buf,
                                                   const float* __restrict__ tab,
                                                   int rstride, int nhshift, float scale) {
  int idx = blockIdx.x * 256 + threadIdx.x;
  int grp = idx & 7;
  int h = (idx >> 3) & ((1 << nhshift) - 1);
  int tok = idx >> (3 + nhshift);
  int s = tok & (S_ - 1);
  u16* p = buf + (size_t)tok * rstride + (h << 7) + grp * 8;
  const float2* tp = (const float2*)tab + (size_t)s * 64 + grp * 8;
  u16x8 lo = *(u16x8*)p;
  u16x8 hi = *(u16x8*)(p + 64);
  u16x8 olo, ohi;
#pragma unroll
  for (int j = 0; j < 8; j++) {
    float2 cs = tp[j];
    float c = cs.x * scale, sn = cs.y * scale;
    float xl = bf2f(lo[j]), xh = bf2f(hi[j]);
    olo[j] = f2bf(xl * c - xh * sn);
    ohi[j] = f2bf(xh * c + xl * sn);
  }
  *(u16x8*)p = olo;
  *(u16x8*)(p + 64) = ohi;
}

// ---------------- QKV GEMM: C = A[M,K] * BT[N,K]^T, BK=32 -------------------
// Q blocks (n0<2048)        -> Qb, stride 2048
// K blocks (2048<=n0<2560)  -> KVb (K-only), stride 512
// V blocks (n0>=2560)       -> V^T LDS-bounce -> Vt[b*512+d][s] (no interleaved V)
__global__ __launch_bounds__(256) void gemm_bt1(const u16* __restrict__ A,
                                                const u16* __restrict__ BT,
                                                u16* __restrict__ Qb,
                                                u16* __restrict__ KVb,
                                                u16* __restrict__ Vt,
                                                int M, int N, int K) {
  __shared__ u16 shm[16384];  // 32KB: As | Bs during K-loop; V^T tile in epilogue
  u16* As = shm;
  u16* Bs = shm + 8192;
  const int Mt = M >> 7;
  const int nwg = gridDim.x;
  int wg = (blockIdx.x & 7) * (nwg >> 3) + (blockIdx.x >> 3);  // XCD swizzle
  int tm = wg % Mt, tn = wg / Mt;
  const size_t m0 = (size_t)tm << 7, n0 = (size_t)tn << 7;
  const int tid = threadIdx.x;
  const int w = tid >> 6, lane = tid & 63;
  const int g = lane >> 4, l15 = lane & 15;
  const int wr = w >> 1, wc = w & 1;

  const int r0 = tid >> 2, s0 = tid & 3;
  const int r1 = (tid + 256) >> 2, s1 = (tid + 256) & 3;
  const u16* Ar0 = A + (m0 + r0) * K + s0 * 8;
  const u16* Ar1 = A + (m0 + r1) * K + s1 * 8;
  const u16* Br0 = BT + (n0 + r0) * K + s0 * 8;
  const u16* Br1 = BT + (n0 + r1) * K + s1 * 8;

  const f32x4 Z4 = {0.f, 0.f, 0.f, 0.f};
  f32x4 acc[4][4];
#pragma unroll
  for (int m = 0; m < 4; m++)
#pragma unroll
    for (int n = 0; n < 4; n++) acc[m][n] = Z4;

  gl2lds16(Ar0, &As[w * 512]);
  gl2lds16(Ar1, &As[w * 512 + 2048]);
  gl2lds16(Br0, &Bs[w * 512]);
  gl2lds16(Br1, &Bs[w * 512 + 2048]);

  const int nk = K >> 5;
  int cur = 0;
  for (int t = 0; t < nk; ++t) {
    if (t + 1 < nk) {
      const int k0 = (t + 1) << 5;
      const int nb = (cur ^ 1) << 12;
      gl2lds16(Ar0 + k0, &As[nb + w * 512]);
      gl2lds16(Ar1 + k0, &As[nb + w * 512 + 2048]);
      gl2lds16(Br0 + k0, &Bs[nb + w * 512]);
      gl2lds16(Br1 + k0, &Bs[nb + w * 512 + 2048]);
      asm volatile("s_waitcnt vmcnt(4)" ::: "memory");
    } else {
      asm volatile("s_waitcnt vmcnt(0)" ::: "memory");
    }
    __builtin_amdgcn_sched_barrier(0);
    __builtin_amdgcn_s_barrier();
    __builtin_amdgcn_sched_barrier(0);
    const int cb = cur << 12;
    bf16x8 af[4], bfr[4];
#pragma unroll
    for (int m = 0; m < 4; m++)
      af[m] = *(const bf16x8*)&As[cb + (wr * 64 + m * 16 + l15) * 32 + g * 8];
#pragma unroll
    for (int n = 0; n < 4; n++)
      bfr[n] = *(const bf16x8*)&Bs[cb + (wc * 64 + n * 16 + l15) * 32 + g * 8];
#pragma unroll
    for (int m = 0; m < 4; m++)
#pragma unroll
      for (int n = 0; n < 4; n++) acc[m][n] = mfma16(af[m], bfr[n], acc[m][n]);
    __builtin_amdgcn_sched_barrier(0);
    __builtin_amdgcn_s_barrier();
    __builtin_amdgcn_sched_barrier(0);
    cur ^= 1;
  }

  if (n0 >= 2560) {
    // V block: LDS-bounce transpose of the 128s x 128d tile -> Vt[d][s].
    // shm layout: row d (256B = 32 8B-slots of 4 u16), slot ^= (d&15).
#pragma unroll
    for (int m = 0; m < 4; m++)
#pragma unroll
      for (int n = 0; n < 4; n++) {
        int d_loc = wc * 64 + n * 16 + l15;
        int slot = (wr * 16 + m * 4 + g) ^ (d_loc & 15);  // s4 = s_loc/4
        u16x4 v;
#pragma unroll
        for (int r = 0; r < 4; r++) v[r] = f2bf(acc[m][n][r]);
        *(u16x4*)&shm[d_loc * 128 + slot * 4] = v;
      }
    __syncthreads();
    const int hi = tid >> 4, lo = tid & 15;
    const size_t bb = m0 >> 11;
    const size_t sbase = (m0 & 2047) + lo * 8;
#pragma unroll
    for (int c = 0; c < 8; ++c) {
      int d_loc = c * 16 + hi;
      int sw = d_loc & 15;
      u16x4 va = *(const u16x4*)&shm[d_loc * 128 + ((lo * 2) ^ sw) * 4];
      u16x4 vb = *(const u16x4*)&shm[d_loc * 128 + ((lo * 2 + 1) ^ sw) * 4];
      u16x8 o;
      o[0] = va[0]; o[1] = va[1]; o[2] = va[2]; o[3] = va[3];
      o[4] = vb[0]; o[5] = vb[1]; o[6] = vb[2]; o[7] = vb[3];
      size_t dg = (size_t)(n0 - 2560) + d_loc;
      *(u16x8*)&Vt[(bb * 512 + dg) * 2048 + sbase] = o;
    }
  } else {
    u16* C;
    size_t cs, cbase;
    if (n0 < 2048) { C = Qb; cs = 2048; cbase = n0; }
    else           { C = KVb; cs = 512; cbase = n0 - 2048; }
#pragma unroll
    for (int m = 0; m < 4; m++)
#pragma unroll
      for (int n = 0; n < 4; n++)
#pragma unroll
        for (int r = 0; r < 4; r++) {
          size_t row = m0 + wr * 64 + m * 16 + g * 4 + r;
          C[row * cs + cbase + wc * 64 + n * 16 + l15] = f2bf(acc[m][n][r]);
        }
  }
}

// ---------------- O-projection GEMM: BK=64, swizzled LDS, f32 out -----------
__global__ __launch_bounds__(256) void gemm_o64(const u16* __restrict__ A,
                                                const u16* __restrict__ BT,
                                                float* __restrict__ C) {
  const int K = 2048, N = 2048;
  __shared__ u16 As[2 * 128 * 64];  // 32KB
  __shared__ u16 Bs[2 * 128 * 64];  // 32KB
  const int Mt = 32;
  const int nwg = gridDim.x;  // 512
  int wg = (blockIdx.x & 7) * (nwg >> 3) + (blockIdx.x >> 3);  // XCD swizzle
  int tm = wg % Mt, tn = wg / Mt;
  const size_t m0 = (size_t)tm << 7, n0 = (size_t)tn << 7;
  const int tid = threadIdx.x;
  const int w = tid >> 6, lane = tid & 63;
  const int g = lane >> 4, l15 = lane & 15;
  const int wr = w >> 1, wc = w & 1;

  size_t aoff[4], boff[4];
#pragma unroll
  for (int ro = 0; ro < 4; ++ro) {
    int c = ro * 256 + tid;
    int row = c >> 3, seg = c & 7;
    aoff[ro] = (m0 + row) * (size_t)K + 8 * (seg ^ (row & 7));
    boff[ro] = (n0 + row) * (size_t)K + 8 * (seg ^ (row & 7));
  }

  const f32x4 Z4 = {0.f, 0.f, 0.f, 0.f};
  f32x4 acc[4][4];
#pragma unroll
  for (int m = 0; m < 4; m++)
#pragma unroll
    for (int n = 0; n < 4; n++) acc[m][n] = Z4;

#pragma unroll
  for (int ro = 0; ro < 4; ++ro) {
    gl2lds16(A + aoff[ro], &As[ro * 2048 + w * 512]);
    gl2lds16(BT + boff[ro], &Bs[ro * 2048 + w * 512]);
  }

  const int nk = K >> 6;  // 32
  int cur = 0;
  for (int t = 0; t < nk; ++t) {
    if (t + 1 < nk) {
      const int k0 = (t + 1) << 6;
      const int nb = (cur ^ 1) << 13;
#pragma unroll
      for (int ro = 0; ro < 4; ++ro) {
        gl2lds16(A + k0 + aoff[ro], &As[nb + ro * 2048 + w * 512]);
        gl2lds16(BT + k0 + boff[ro], &Bs[nb + ro * 2048 + w * 512]);
      }
      asm volatile("s_waitcnt vmcnt(8)" ::: "memory");
    } else {
      asm volatile("s_waitcnt vmcnt(0)" ::: "memory");
    }
    __builtin_amdgcn_sched_barrier(0);
    __builtin_amdgcn_s_barrier();
    __builtin_amdgcn_sched_barrier(0);
    const int cb = cur << 13;
    bf16x8 af[2][4], bfr[2][4];
#pragma unroll
    for (int kk = 0; kk < 2; ++kk) {
#pragma unroll
      for (int m = 0; m < 4; m++)
        af[kk][m] = *(const bf16x8*)&As[cb + (wr * 64 + m * 16 + l15) * 64 +
                                       ((kk * 4 + g) ^ (l15 & 7)) * 8];
#pragma unroll
      for (int n = 0; n < 4; n++)
        bfr[kk][n] = *(const bf16x8*)&Bs[cb + (wc * 64 + n * 16 + l15) * 64 +
                                        ((kk * 4 + g) ^ (l15 & 7)) * 8];
    }
#pragma unroll
    for (int kk = 0; kk < 2; ++kk)
#pragma unroll
      for (int m = 0; m < 4; m++)
#pragma unroll
        for (int n = 0; n < 4; n++)
          acc[m][n] = mfma16(af[kk][m], bfr[kk][n], acc[m][n]);
    __builtin_amdgcn_sched_barrier(0);
    __builtin_amdgcn_s_barrier();
    __builtin_amdgcn_sched_barrier(0);
    cur ^= 1;
  }

#pragma unroll
  for (int m = 0; m < 4; m++)
#pragma unroll
    for (int n = 0; n < 4; n++)
#pragma unroll
      for (int r = 0; r < 4; r++) {
        size_t row = m0 + wr * 64 + m * 16 + g * 4 + r;
        size_t col = n0 + wc * 64 + n * 16 + l15;
        C[row * (size_t)N + col] = acc[m][n][r];
      }
}

// ---------------- flash attention (R24 structure; K stride 512) -------------
// Qb: [B*S, 2048] bf16 RAW; KVb: [B*S, 512] bf16 K-only (RoPE'd);
// Vt: [B*512][2048] bf16; Ob: bf16. Q-RoPE fused at Q load.
__global__ __launch_bounds__(256) void attn_kernel(const u16* __restrict__ Qb,
                                                   const u16* __restrict__ KVb,
                                                   const u16* __restrict__ Vt,
                                                   const float* __restrict__ tab,
                                                   u16* __restrict__ Ob) {
  __shared__ u16 Ks[2][64 * 128];
  __shared__ u16 Vs[2][128 * 64];
  __shared__ u16 Ps[4][16 * 72];
  const int pair = blockIdx.x, h = blockIdx.y, b = blockIdx.z;
  const int kvh = h >> 2;
  const int tid = threadIdx.x, w = tid >> 6, lane = tid & 63;
  const int g = lane >> 4, l15 = lane & 15;
  const f32x4 Z4 = {0.f, 0.f, 0.f, 0.f};
  u16x8 oneu;
#pragma unroll
  for (int j = 0; j < 8; j++) oneu[j] = 0x3f80;
  const bf16x8 ones = __builtin_bit_cast(bf16x8, oneu);

  const u16* Kbase = KVb + (size_t)b * S_ * 512 + kvh * 128;
  const u16* Vbase = Vt + (size_t)(b * NKV_ + kvh) * HD_ * 2048;

  for (int half = 0; half < 2; ++half) {
    const int qt = half ? pair : 31 - pair;
    const int qrow0 = qt * 64 + w * 16;

    bf16x8 qf[4];
    const u16* qp = Qb + (size_t)(b * S_ + qrow0 + l15) * 2048 + h * 128;
#pragma unroll
    for (int ds = 0; ds < 4; ds++) qf[ds] = *(const bf16x8*)(qp + ds * 32 + g * 8);
    // fused Q-RoPE (+ QSCALE fold): rotate (d, d+64) pairs in-register
    {
      const float2* tq = (const float2*)tab + (size_t)(qrow0 + l15) * 64 + g * 8;
#pragma unroll
      for (int ds = 0; ds < 2; ds++) {
        u16x8 a = __builtin_bit_cast(u16x8, qf[ds]);
        u16x8 bb = __builtin_bit_cast(u16x8, qf[ds + 2]);
#pragma unroll
        for (int j = 0; j < 8; j++) {
          float2 cs = tq[ds * 32 + j];  // freq idx = ds*32 + g*8 + j
          float c = cs.x * QSCALE, sn = cs.y * QSCALE;
          float lo = bf2f(a[j]), hi = bf2f(bb[j]);
          a[j] = f2bf(lo * c - hi * sn);
          bb[j] = f2bf(hi * c + lo * sn);
        }
        qf[ds] = __builtin_bit_cast(bf16x8, a);
        qf[ds + 2] = __builtin_bit_cast(bf16x8, bb);
      }
    }

    float m_r[4], l_r[4];
    f32x4 oa[8];
#pragma unroll
    for (int r = 0; r < 4; r++) { m_r[r] = -1e30f; l_r[r] = 0.f; }
#pragma unroll
    for (int n = 0; n < 8; n++) oa[n] = Z4;

    const int nt = qt + 1;
#pragma unroll
    for (int ro = 0; ro < 4; ++ro) {
      int c = ro * 256 + tid;
      int kv = c >> 4, p = c & 15;
      gl2lds16(Kbase + (size_t)kv * 512 + 8 * (p ^ (kv & 15)), &Ks[0][ro * 2048 + w * 512]);
      int d = c >> 3, p2 = c & 7;
      gl2lds16(Vbase + (size_t)d * 2048 + 8 * (p2 ^ (d & 7)), &Vs[0][ro * 2048 + w * 512]);
    }
    __syncthreads();
    int cur = 0;

    for (int t = 0; t < nt; ++t) {
      const int kv0 = t * 64;
      if (t + 1 < nt) {
        const int nkv0 = kv0 + 64;
#pragma unroll
        for (int ro = 0; ro < 4; ++ro) {
          int c = ro * 256 + tid;
          int kv = c >> 4, p = c & 15;
          gl2lds16(Kbase + (size_t)(nkv0 + kv) * 512 + 8 * (p ^ (kv & 15)),
                   &Ks[cur ^ 1][ro * 2048 + w * 512]);
          int d = c >> 3, p2 = c & 7;
          gl2lds16(Vbase + (size_t)d * 2048 + nkv0 + 8 * (p2 ^ (d & 7)),
                   &Vs[cur ^ 1][ro * 2048 + w * 512]);
        }
      }

      f32x4 sa[4];
#pragma unroll
      for (int c16 = 0; c16 < 4; c16++) sa[c16] = Z4;
      __builtin_amdgcn_s_setprio(1);
#pragma unroll
      for (int ds = 0; ds < 4; ++ds) {
#pragma unroll
        for (int c16 = 0; c16 < 4; ++c16) {
          bf16x8 kf = *(const bf16x8*)&Ks[cur][(c16 * 16 + l15) * 128 + ((ds * 4 + g) ^ l15) * 8];
          sa[c16] = mfma16(qf[ds], kf, sa[c16]);
        }
      }
      __builtin_amdgcn_s_setprio(0);

      if (kv0 + 63 > qrow0) {
#pragma unroll
        for (int c16 = 0; c16 < 4; c16++)
#pragma unroll
          for (int r = 0; r < 4; r++) {
            if (kv0 + c16 * 16 + l15 > qrow0 + g * 4 + r) sa[c16][r] = -1e30f;
          }
      }

      float lmax[4];
#pragma unroll
      for (int r = 0; r < 4; r++)
        lmax[r] = fmaxf(fmaxf(sa[0][r], sa[1][r]), fmaxf(sa[2][r], sa[3][r]));
      bool need = (lmax[0] > m_r[0] + 11.5415603f) || (lmax[1] > m_r[1] + 11.5415603f) ||
                  (lmax[2] > m_r[2] + 11.5415603f) || (lmax[3] > m_r[3] + 11.5415603f);
      if (__any(need)) {
        float pm[4];
#pragma unroll
        for (int r = 0; r < 4; r++) pm[r] = lmax[r];
#pragma unroll
        for (int off = 1; off < 16; off <<= 1)
#pragma unroll
          for (int r = 0; r < 4; r++) pm[r] = fmaxf(pm[r], __shfl_xor(pm[r], off));
#pragma unroll
        for (int r = 0; r < 4; r++) {
          float mn = fmaxf(m_r[r], pm[r]);
          float corr = exp2f(m_r[r] - mn);
          m_r[r] = mn;
          l_r[r] *= corr;
#pragma unroll
          for (int n = 0; n < 8; n++) oa[n][r] *= corr;
        }
      }

#pragma unroll
      for (int c16 = 0; c16 < 4; c16++)
#pragma unroll
        for (int r = 0; r < 4; r++)
          Ps[w][(g * 4 + r) * 72 + c16 * 16 + l15] =
              f2bf(exp2f(sa[c16][r] - m_r[r]));
      asm volatile("s_waitcnt lgkmcnt(0)" ::: "memory");
      __builtin_amdgcn_sched_barrier(0);

      f32x4 srow = Z4;
      __builtin_amdgcn_s_setprio(1);
#pragma unroll
      for (int ks = 0; ks < 2; ++ks) {
        bf16x8 pa = *(const bf16x8*)&Ps[w][l15 * 72 + ks * 32 + g * 8];
        srow = mfma16(pa, ones, srow);
#pragma unroll
        for (int n = 0; n < 8; n++) {
          bf16x8 vf = *(const bf16x8*)&Vs[cur][(n * 16 + l15) * 64 + (((ks * 4 + g) ^ (l15 & 7))) * 8];
          oa[n] = mfma16(pa, vf, oa[n]);
        }
      }
      __builtin_amdgcn_s_setprio(0);
#pragma unroll
      for (int r = 0; r < 4; r++) l_r[r] += srow[r];

      __syncthreads();
      cur ^= 1;
    }

    float inv[4];
#pragma unroll
    for (int r = 0; r < 4; r++) inv[r] = 1.0f / l_r[r];
#pragma unroll
    for (int n = 0; n < 8; n++)
#pragma unroll
      for (int r = 0; r < 4; r++) {
        size_t row = (size_t)b * S_ + qrow0 + g * 4 + r;
        Ob[row * 2048 + h * 128 + n * 16 + l15] = f2bf(oa[n][r] * inv[r]);
      }
  }
}

extern "C" void kernel_launch(void* const* d_in, const int* in_sizes, int n_in,
                              void* d_out, int out_size, void* d_ws, size_t ws_size,
                              hipStream_t stream) {
  const float* hid = (const float*)d_in[0];
  // d_in[1] = attention_mask: exactly causal; implemented directly in attn_kernel.
  const float* wq = (const float*)d_in[2];
  const float* wk = (const float*)d_in[3];
  const float* wv = (const float*)d_in[4];
  const float* wo = (const float*)d_in[5];
  float* out = (float*)d_out;
  char* ws = (char*)d_ws;

  // workspace layout (52 MB total)
  u16* hb     = (u16*)(ws);                   // 16MB: hidden bf16 -> later attn output
  u16* wqkvT  = (u16*)(ws + (16u << 20));     // 12MB: [wqT;wkT;wvT] (3072 x 2048)
  float* tab  = (float*)(ws + (20u << 20));   //  1MB: rope table (live until attn; inside dead wqkvT)
  u16* woT    = (u16*)(ws + (20u << 20));     //  8MB: written AFTER attn (overwrites tab)
  u16* Qb     = (u16*)(ws + (28u << 20));     // 16MB
  u16* KVb    = (u16*)(ws + (44u << 20));     //  4MB: K only, stride 512
  u16* Vt     = (u16*)(ws + (48u << 20));     //  4MB: V^T, written by gemm_bt1

  cvt_f32_bf16<<<4096, 256, 0, stream>>>(hid, hb);
  transpose_qkv<<<dim3(96, 64), 256, 0, stream>>>(wq, wk, wv, wqkvT);

  // fused QKV projection: Qb | KVb (K) | Vt (V transposed in-epilogue)
  gemm_bt1<<<768, 256, 0, stream>>>(hb, wqkvT, Qb, KVb, Vt, 4096, 3072, 2048);

  // RoPE table; K rotated in place. Q-RoPE fused into attn_kernel.
  rope_table<<<512, 256, 0, stream>>>(tab);
  rope_kernel<<<512, 256, 0, stream>>>(KVb, tab, 512, 2, 1.0f);

  attn_kernel<<<dim3(16, 16, 2), 256, 0, stream>>>(Qb, KVb, Vt, tab, hb);

  // woT overwrites the table region -- safe only after attn has run.
  transpose_f32_bf16<<<dim3(64, 64), 256, 0, stream>>>(wo, woT, 2048, 2048);

  gemm_o64<<<512, 256, 0, stream>>>(hb, woT, out);
}

// Round 26
// 224.792 us; speedup vs baseline: 1.0004x; 1.0004x over previous
//
#include <hip/hip_runtime.h>

typedef unsigned short u16;
typedef unsigned int u32;
typedef __attribute__((ext_vector_type(8))) __bf16 bf16x8;
typedef __attribute__((ext_vector_type(8))) u16 u16x8;
typedef __attribute__((ext_vector_type(4))) float f32x4;

#define B_ 2
#define S_ 2048
#define H_ 2048
#define NH_ 16
#define NKV_ 4
#define HD_ 128
#define QSCALE 0.1275179064f  // log2(e)/sqrt(128) -> log2-domain scores

__device__ __forceinline__ u16 f2bf(float f) {
  return __builtin_bit_cast(u16, static_cast<__bf16>(f));
}
__device__ __forceinline__ float bf2f(u16 v) {
  return __builtin_bit_cast(float, (u32)v << 16);
}
__device__ __forceinline__ void gl2lds16(const void* g, void* l) {
  __builtin_amdgcn_global_load_lds((const __attribute__((address_space(1))) u32*)g,
                                   (__attribute__((address_space(3))) u32*)l, 16, 0, 0);
}
__device__ __forceinline__ f32x4 mfma16(bf16x8 a, bf16x8 b, f32x4 c) {
  return __builtin_amdgcn_mfma_f32_16x16x32_bf16(a, b, c, 0, 0, 0);
}

// ---------------- fp32 -> bf16 convert (vectorized) ----------------
__global__ __launch_bounds__(256) void cvt_f32_bf16(const float* __restrict__ in,
                                                    u16* __restrict__ out) {
  size_t i = ((size_t)blockIdx.x * 256 + threadIdx.x) * 8;
  const float4* p = (const float4*)(in + i);
  float4 a = p[0], b = p[1];
  u16x8 o;
  o[0] = f2bf(a.x); o[1] = f2bf(a.y); o[2] = f2bf(a.z); o[3] = f2bf(a.w);
  o[4] = f2bf(b.x); o[5] = f2bf(b.y); o[6] = f2bf(b.z); o[7] = f2bf(b.w);
  *(u16x8*)(out + i) = o;
}

// ---------------- fused weight transpose: wq|wk|wv (f32) -> wqkvT (bf16) ----
__global__ __launch_bounds__(256) void transpose_qkv(const float* __restrict__ wq,
                                                     const float* __restrict__ wk,
                                                     const float* __restrict__ wv,
                                                     u16* __restrict__ out) {
  __shared__ float tl[32][33];
  int bx = blockIdx.x, by = blockIdx.y;
  int tx = threadIdx.x & 31, ty = threadIdx.x >> 5;
  int orow0 = bx * 32;
  const float* src;
  int scol0, C;
  if (orow0 < 2048)      { src = wq; scol0 = orow0;        C = 2048; }
  else if (orow0 < 2560) { src = wk; scol0 = orow0 - 2048; C = 512; }
  else                   { src = wv; scol0 = orow0 - 2560; C = 512; }
#pragma unroll
  for (int i = 0; i < 32; i += 8)
    tl[ty + i][tx] = src[(size_t)(by * 32 + ty + i) * C + scol0 + tx];
  __syncthreads();
#pragma unroll
  for (int i = 0; i < 32; i += 8)
    out[(size_t)(orow0 + ty + i) * 2048 + by * 32 + tx] = f2bf(tl[tx][ty + i]);
}

// ---------------- transpose fp32 [R][C] -> bf16 [C][R] ----------------
__global__ __launch_bounds__(256) void transpose_f32_bf16(const float* __restrict__ in,
                                                          u16* __restrict__ out,
                                                          int R, int C) {
  __shared__ float tl[32][33];
  int bx = blockIdx.x, by = blockIdx.y;
  int tx = threadIdx.x & 31, ty = threadIdx.x >> 5;
#pragma unroll
  for (int i = 0; i < 32; i += 8)
    tl[ty + i][tx] = in[(size_t)(by * 32 + ty + i) * C + bx * 32 + tx];
  __syncthreads();
#pragma unroll
  for (int i = 0; i < 32; i += 8)
    out[(size_t)(bx * 32 + ty + i) * R + by * 32 + tx] = f2bf(tl[tx][ty + i]);
}

// ---------------- transpose V part of KV buffer: bf16 -> Vt[b][512 d][2048 s] ----------------
__global__ __launch_bounds__(256) void transpose_v(const u16* __restrict__ kvb,
                                                   u16* __restrict__ vt) {
  __shared__ u16 tl[32][33];
  int sx = blockIdx.x, dx = blockIdx.y, b = blockIdx.z;
  int tx = threadIdx.x & 31, ty = threadIdx.x >> 5;
#pragma unroll
  for (int i = 0; i < 32; i += 8)
    tl[ty + i][tx] = kvb[(size_t)(b * S_ + sx * 32 + ty + i) * 1024 + 512 + dx * 32 + tx];
  __syncthreads();
#pragma unroll
  for (int i = 0; i < 32; i += 8)
    vt[(size_t)(b * 512 + dx * 32 + ty + i) * 2048 + sx * 32 + tx] = tl[tx][ty + i];
}

// ---------------- RoPE cos/sin table: tab[s][i] = {cos,sin}(s * 10000^(-i/64))
__global__ __launch_bounds__(256) void rope_table(float* __restrict__ tab) {
  int idx = blockIdx.x * 256 + threadIdx.x;  // 131072 = 2048 x 64
  int s = idx >> 6, i = idx & 63;
  float inv = exp2f((float)i * -0.20762050593045702f);
  float ang = (float)s * inv;
  tab[2 * idx] = cosf(ang);
  tab[2 * idx + 1] = sinf(ang);
}

// ---------------- RoPE in place on bf16 buffer (table-driven; K only) --------
__global__ __launch_bounds__(256) void rope_kernel(u16* __restrict__ buf,
                                                   const float* __restrict__ tab,
                                                   int rstride, int nhshift, float scale) {
  int idx = blockIdx.x * 256 + threadIdx.x;
  int grp = idx & 7;
  int h = (idx >> 3) & ((1 << nhshift) - 1);
  int tok = idx >> (3 + nhshift);
  int s = tok & (S_ - 1);
  u16* p = buf + (size_t)tok * rstride + (h << 7) + grp * 8;
  const float2* tp = (const float2*)tab + (size_t)s * 64 + grp * 8;
  u16x8 lo = *(u16x8*)p;
  u16x8 hi = *(u16x8*)(p + 64);
  u16x8 olo, ohi;
#pragma unroll
  for (int j = 0; j < 8; j++) {
    float2 cs = tp[j];
    float c = cs.x * scale, sn = cs.y * scale;
    float xl = bf2f(lo[j]), xh = bf2f(hi[j]);
    olo[j] = f2bf(xl * c - xh * sn);
    ohi[j] = f2bf(xh * c + xl * sn);
  }
  *(u16x8*)p = olo;
  *(u16x8*)(p + 64) = ohi;
}

// ---------------- bf16 GEMM (QKV): C = A[M,K] * BT[N,K]^T, BK=32 ------------
__global__ __launch_bounds__(256) void gemm_bt1(const u16* __restrict__ A,
                                                const u16* __restrict__ BT,
                                                u16* __restrict__ Qb,
                                                u16* __restrict__ KVb,
                                                int M, int N, int K) {
  __shared__ u16 As[2 * 128 * 32];  // 16KB
  __shared__ u16 Bs[2 * 128 * 32];  // 16KB
  const int Mt = M >> 7;
  const int nwg = gridDim.x;
  int wg = (blockIdx.x & 7) * (nwg >> 3) + (blockIdx.x >> 3);  // XCD swizzle
  int tm = wg % Mt, tn = wg / Mt;
  const size_t m0 = (size_t)tm << 7, n0 = (size_t)tn << 7;
  const int tid = threadIdx.x;
  const int w = tid >> 6, lane = tid & 63;
  const int g = lane >> 4, l15 = lane & 15;
  const int wr = w >> 1, wc = w & 1;

  const int r0 = tid >> 2, s0 = tid & 3;
  const int r1 = (tid + 256) >> 2, s1 = (tid + 256) & 3;
  const u16* Ar0 = A + (m0 + r0) * K + s0 * 8;
  const u16* Ar1 = A + (m0 + r1) * K + s1 * 8;
  const u16* Br0 = BT + (n0 + r0) * K + s0 * 8;
  const u16* Br1 = BT + (n0 + r1) * K + s1 * 8;

  const f32x4 Z4 = {0.f, 0.f, 0.f, 0.f};
  f32x4 acc[4][4];
#pragma unroll
  for (int m = 0; m < 4; m++)
#pragma unroll
    for (int n = 0; n < 4; n++) acc[m][n] = Z4;

  gl2lds16(Ar0, &As[w * 512]);
  gl2lds16(Ar1, &As[w * 512 + 2048]);
  gl2lds16(Br0, &Bs[w * 512]);
  gl2lds16(Br1, &Bs[w * 512 + 2048]);

  const int nk = K >> 5;
  int cur = 0;
  for (int t = 0; t < nk; ++t) {
    if (t + 1 < nk) {
      const int k0 = (t + 1) << 5;
      const int nb = (cur ^ 1) << 12;
      gl2lds16(Ar0 + k0, &As[nb + w * 512]);
      gl2lds16(Ar1 + k0, &As[nb + w * 512 + 2048]);
      gl2lds16(Br0 + k0, &Bs[nb + w * 512]);
      gl2lds16(Br1 + k0, &Bs[nb + w * 512 + 2048]);
      asm volatile("s_waitcnt vmcnt(4)" ::: "memory");
    } else {
      asm volatile("s_waitcnt vmcnt(0)" ::: "memory");
    }
    __builtin_amdgcn_sched_barrier(0);
    __builtin_amdgcn_s_barrier();
    __builtin_amdgcn_sched_barrier(0);
    const int cb = cur << 12;
    bf16x8 af[4], bfr[4];
#pragma unroll
    for (int m = 0; m < 4; m++)
      af[m] = *(const bf16x8*)&As[cb + (wr * 64 + m * 16 + l15) * 32 + g * 8];
#pragma unroll
    for (int n = 0; n < 4; n++)
      bfr[n] = *(const bf16x8*)&Bs[cb + (wc * 64 + n * 16 + l15) * 32 + g * 8];
#pragma unroll
    for (int m = 0; m < 4; m++)
#pragma unroll
      for (int n = 0; n < 4; n++) acc[m][n] = mfma16(af[m], bfr[n], acc[m][n]);
    __builtin_amdgcn_sched_barrier(0);
    __builtin_amdgcn_s_barrier();
    __builtin_amdgcn_sched_barrier(0);
    cur ^= 1;
  }

  u16* C;
  size_t cs, cbase;
  if (n0 < 2048) { C = Qb; cs = 2048; cbase = n0; }
  else           { C = KVb; cs = 1024; cbase = n0 - 2048; }
#pragma unroll
  for (int m = 0; m < 4; m++)
#pragma unroll
    for (int n = 0; n < 4; n++)
#pragma unroll
      for (int r = 0; r < 4; r++) {
        size_t row = m0 + wr * 64 + m * 16 + g * 4 + r;
        C[row * cs + cbase + wc * 64 + n * 16 + l15] = f2bf(acc[m][n][r]);
      }
}

// ---------------- O-projection GEMM: BK=64, swizzled LDS, f32 out -----------
__global__ __launch_bounds__(256) void gemm_o64(const u16* __restrict__ A,
                                                const u16* __restrict__ BT,
                                                float* __restrict__ C) {
  const int K = 2048, N = 2048;
  __shared__ u16 As[2 * 128 * 64];  // 32KB
  __shared__ u16 Bs[2 * 128 * 64];  // 32KB
  const int Mt = 32;
  const int nwg = gridDim.x;  // 512
  int wg = (blockIdx.x & 7) * (nwg >> 3) + (blockIdx.x >> 3);  // XCD swizzle
  int tm = wg % Mt, tn = wg / Mt;
  const size_t m0 = (size_t)tm << 7, n0 = (size_t)tn << 7;
  const int tid = threadIdx.x;
  const int w = tid >> 6, lane = tid & 63;
  const int g = lane >> 4, l15 = lane & 15;
  const int wr = w >> 1, wc = w & 1;

  size_t aoff[4], boff[4];
#pragma unroll
  for (int ro = 0; ro < 4; ++ro) {
    int c = ro * 256 + tid;
    int row = c >> 3, seg = c & 7;
    aoff[ro] = (m0 + row) * (size_t)K + 8 * (seg ^ (row & 7));
    boff[ro] = (n0 + row) * (size_t)K + 8 * (seg ^ (row & 7));
  }

  const f32x4 Z4 = {0.f, 0.f, 0.f, 0.f};
  f32x4 acc[4][4];
#pragma unroll
  for (int m = 0; m < 4; m++)
#pragma unroll
    for (int n = 0; n < 4; n++) acc[m][n] = Z4;

#pragma unroll
  for (int ro = 0; ro < 4; ++ro) {
    gl2lds16(A + aoff[ro], &As[ro * 2048 + w * 512]);
    gl2lds16(BT + boff[ro], &Bs[ro * 2048 + w * 512]);
  }

  const int nk = K >> 6;  // 32
  int cur = 0;
  for (int t = 0; t < nk; ++t) {
    if (t + 1 < nk) {
      const int k0 = (t + 1) << 6;
      const int nb = (cur ^ 1) << 13;
#pragma unroll
      for (int ro = 0; ro < 4; ++ro) {
        gl2lds16(A + k0 + aoff[ro], &As[nb + ro * 2048 + w * 512]);
        gl2lds16(BT + k0 + boff[ro], &Bs[nb + ro * 2048 + w * 512]);
      }
      asm volatile("s_waitcnt vmcnt(8)" ::: "memory");
    } else {
      asm volatile("s_waitcnt vmcnt(0)" ::: "memory");
    }
    __builtin_amdgcn_sched_barrier(0);
    __builtin_amdgcn_s_barrier();
    __builtin_amdgcn_sched_barrier(0);
    const int cb = cur << 13;
    bf16x8 af[2][4], bfr[2][4];
#pragma unroll
    for (int kk = 0; kk < 2; ++kk) {
#pragma unroll
      for (int m = 0; m < 4; m++)
        af[kk][m] = *(const bf16x8*)&As[cb + (wr * 64 + m * 16 + l15) * 64 +
                                       ((kk * 4 + g) ^ (l15 & 7)) * 8];
#pragma unroll
      for (int n = 0; n < 4; n++)
        bfr[kk][n] = *(const bf16x8*)&Bs[cb + (wc * 64 + n * 16 + l15) * 64 +
                                        ((kk * 4 + g) ^ (l15 & 7)) * 8];
    }
#pragma unroll
    for (int kk = 0; kk < 2; ++kk)
#pragma unroll
      for (int m = 0; m < 4; m++)
#pragma unroll
        for (int n = 0; n < 4; n++)
          acc[m][n] = mfma16(af[kk][m], bfr[kk][n], acc[m][n]);
    __builtin_amdgcn_sched_barrier(0);
    __builtin_amdgcn_s_barrier();
    __builtin_amdgcn_sched_barrier(0);
    cur ^= 1;
  }

#pragma unroll
  for (int m = 0; m < 4; m++)
#pragma unroll
    for (int n = 0; n < 4; n++)
#pragma unroll
      for (int r = 0; r < 4; r++) {
        size_t row = m0 + wr * 64 + m * 16 + g * 4 + r;
        size_t col = n0 + wc * 64 + n * 16 + l15;
        C[row * (size_t)N + col] = acc[m][n][r];
      }
}

// ---------------- flash attention (R15 structure + fused Q-RoPE) ------------
// Qb: [B*S, 2048] bf16 RAW; KVb: [B*S, 1024] bf16 (K RoPE'd | V);
// Vt: [B*512][2048] bf16; Ob: bf16. Q-RoPE fused at Q load (freq = ds*32+g*8+j).
__global__ __launch_bounds__(256) void attn_kernel(const u16* __restrict__ Qb,
                                                   const u16* __restrict__ KVb,
                                                   const u16* __restrict__ Vt,
                                                   const float* __restrict__ tab,
                                                   u16* __restrict__ Ob) {
  __shared__ u16 Ks[2][64 * 128];
  __shared__ u16 Vs[2][128 * 64];
  __shared__ u16 Ps[4][16 * 72];
  const int pair = blockIdx.x, h = blockIdx.y, b = blockIdx.z;
  const int kvh = h >> 2;
  const int tid = threadIdx.x, w = tid >> 6, lane = tid & 63;
  const int g = lane >> 4, l15 = lane & 15;
  const f32x4 Z4 = {0.f, 0.f, 0.f, 0.f};
  u16x8 oneu;
#pragma unroll
  for (int j = 0; j < 8; j++) oneu[j] = 0x3f80;
  const bf16x8 ones = __builtin_bit_cast(bf16x8, oneu);

  const u16* Kbase = KVb + (size_t)b * S_ * 1024 + kvh * 128;
  const u16* Vbase = Vt + (size_t)(b * NKV_ + kvh) * HD_ * 2048;

  for (int half = 0; half < 2; ++half) {
    const int qt = half ? pair : 31 - pair;
    const int qrow0 = qt * 64 + w * 16;

    bf16x8 qf[4];
    const u16* qp = Qb + (size_t)(b * S_ + qrow0 + l15) * 2048 + h * 128;
#pragma unroll
    for (int ds = 0; ds < 4; ds++) qf[ds] = *(const bf16x8*)(qp + ds * 32 + g * 8);
    // fused Q-RoPE (+ QSCALE fold): rotate (d, d+64) pairs in-register
    {
      const float2* tq = (const float2*)tab + (size_t)(qrow0 + l15) * 64 + g * 8;
#pragma unroll
      for (int ds = 0; ds < 2; ds++) {
        u16x8 a = __builtin_bit_cast(u16x8, qf[ds]);
        u16x8 bb = __builtin_bit_cast(u16x8, qf[ds + 2]);
#pragma unroll
        for (int j = 0; j < 8; j++) {
          float2 cs = tq[ds * 32 + j];  // freq idx = ds*32 + g*8 + j
          float c = cs.x * QSCALE, sn = cs.y * QSCALE;
          float lo = bf2f(a[j]), hi = bf2f(bb[j]);
          a[j] = f2bf(lo * c - hi * sn);
          bb[j] = f2bf(hi * c + lo * sn);
        }
        qf[ds] = __builtin_bit_cast(bf16x8, a);
        qf[ds + 2] = __builtin_bit_cast(bf16x8, bb);
      }
    }

    float m_r[4], l_r[4];
    f32x4 oa[8];
#pragma unroll
    for (int r = 0; r < 4; r++) { m_r[r] = -1e30f; l_r[r] = 0.f; }
#pragma unroll
    for (int n = 0; n < 8; n++) oa[n] = Z4;

    const int nt = qt + 1;
#pragma unroll
    for (int ro = 0; ro < 4; ++ro) {
      int c = ro * 256 + tid;
      int kv = c >> 4, p = c & 15;
      gl2lds16(Kbase + (size_t)kv * 1024 + 8 * (p ^ (kv & 15)), &Ks[0][ro * 2048 + w * 512]);
      int d = c >> 3, p2 = c & 7;
      gl2lds16(Vbase + (size_t)d * 2048 + 8 * (p2 ^ (d & 7)), &Vs[0][ro * 2048 + w * 512]);
    }
    __syncthreads();
    int cur = 0;

    for (int t = 0; t < nt; ++t) {
      const int kv0 = t * 64;
      if (t + 1 < nt) {
        const int nkv0 = kv0 + 64;
#pragma unroll
        for (int ro = 0; ro < 4; ++ro) {
          int c = ro * 256 + tid;
          int kv = c >> 4, p = c & 15;
          gl2lds16(Kbase + (size_t)(nkv0 + kv) * 1024 + 8 * (p ^ (kv & 15)),
                   &Ks[cur ^ 1][ro * 2048 + w * 512]);
          int d = c >> 3, p2 = c & 7;
          gl2lds16(Vbase + (size_t)d * 2048 + nkv0 + 8 * (p2 ^ (d & 7)),
                   &Vs[cur ^ 1][ro * 2048 + w * 512]);
        }
      }

      f32x4 sa[4];
#pragma unroll
      for (int c16 = 0; c16 < 4; c16++) sa[c16] = Z4;
      __builtin_amdgcn_s_setprio(1);
#pragma unroll
      for (int ds = 0; ds < 4; ++ds) {
#pragma unroll
        for (int c16 = 0; c16 < 4; ++c16) {
          bf16x8 kf = *(const bf16x8*)&Ks[cur][(c16 * 16 + l15) * 128 + ((ds * 4 + g) ^ l15) * 8];
          sa[c16] = mfma16(qf[ds], kf, sa[c16]);
        }
      }
      __builtin_amdgcn_s_setprio(0);

      if (kv0 + 63 > qrow0) {
#pragma unroll
        for (int c16 = 0; c16 < 4; c16++)
#pragma unroll
          for (int r = 0; r < 4; r++) {
            if (kv0 + c16 * 16 + l15 > qrow0 + g * 4 + r) sa[c16][r] = -1e30f;
          }
      }

      float lmax[4];
#pragma unroll
      for (int r = 0; r < 4; r++)
        lmax[r] = fmaxf(fmaxf(sa[0][r], sa[1][r]), fmaxf(sa[2][r], sa[3][r]));
      bool need = (lmax[0] > m_r[0] + 11.5415603f) || (lmax[1] > m_r[1] + 11.5415603f) ||
                  (lmax[2] > m_r[2] + 11.5415603f) || (lmax[3] > m_r[3] + 11.5415603f);
      if (__any(need)) {
        float pm[4];
#pragma unroll
        for (int r = 0; r < 4; r++) pm[r] = lmax[r];
#pragma unroll
        for (int off = 1; off < 16; off <<= 1)
#pragma unroll
          for (int r = 0; r < 4; r++) pm[r] = fmaxf(pm[r], __shfl_xor(pm[r], off));
#pragma unroll
        for (int r = 0; r < 4; r++) {
          float mn = fmaxf(m_r[r], pm[r]);
          float corr = exp2f(m_r[r] - mn);
          m_r[r] = mn;
          l_r[r] *= corr;
#pragma unroll
          for (int n = 0; n < 8; n++) oa[n][r] *= corr;
        }
      }

#pragma unroll
      for (int c16 = 0; c16 < 4; c16++)
#pragma unroll
        for (int r = 0; r < 4; r++)
          Ps[w][(g * 4 + r) * 72 + c16 * 16 + l15] =
              f2bf(exp2f(sa[c16][r] - m_r[r]));
      asm volatile("s_waitcnt lgkmcnt(0)" ::: "memory");
      __builtin_amdgcn_sched_barrier(0);

      f32x4 srow = Z4;
      __builtin_amdgcn_s_setprio(1);
#pragma unroll
      for (int ks = 0; ks < 2; ++ks) {
        bf16x8 pa = *(const bf16x8*)&Ps[w][l15 * 72 + ks * 32 + g * 8];
        srow = mfma16(pa, ones, srow);
#pragma unroll
        for (int n = 0; n < 8; n++) {
          bf16x8 vf = *(const bf16x8*)&Vs[cur][(n * 16 + l15) * 64 + (((ks * 4 + g) ^ (l15 & 7))) * 8];
          oa[n] = mfma16(pa, vf, oa[n]);
        }
      }
      __builtin_amdgcn_s_setprio(0);
#pragma unroll
      for (int r = 0; r < 4; r++) l_r[r] += srow[r];

      __syncthreads();
      cur ^= 1;
    }

    float inv[4];
#pragma unroll
    for (int r = 0; r < 4; r++) inv[r] = 1.0f / l_r[r];
#pragma unroll
    for (int n = 0; n < 8; n++)
#pragma unroll
      for (int r = 0; r < 4; r++) {
        size_t row = (size_t)b * S_ + qrow0 + g * 4 + r;
        Ob[row * 2048 + h * 128 + n * 16 + l15] = f2bf(oa[n][r] * inv[r]);
      }
  }
}

extern "C" void kernel_launch(void* const* d_in, const int* in_sizes, int n_in,
                              void* d_out, int out_size, void* d_ws, size_t ws_size,
                              hipStream_t stream) {
  const float* hid = (const float*)d_in[0];
  // d_in[1] = attention_mask: exactly causal; implemented directly in attn_kernel.
  const float* wq = (const float*)d_in[2];
  const float* wk = (const float*)d_in[3];
  const float* wv = (const float*)d_in[4];
  const float* wo = (const float*)d_in[5];
  float* out = (float*)d_out;
  char* ws = (char*)d_ws;

  // workspace layout (52 MB total)
  u16* hb     = (u16*)(ws);                   // 16MB: hidden bf16 -> later attn output
  u16* wqkvT  = (u16*)(ws + (16u << 20));     // 12MB: [wqT;wkT;wvT] (3072 x 2048)
  u16* Vt     = (u16*)(ws + (16u << 20));     //  4MB: reuse after QKV GEMM
  float* tab  = (float*)(ws + (20u << 20));   //  1MB: rope table (live until attn)
  u16* woT    = (u16*)(ws + (20u << 20));     //  8MB: written AFTER attn (overwrites tab)
  u16* Qb     = (u16*)(ws + (28u << 20));     // 16MB
  u16* KVb    = (u16*)(ws + (44u << 20));     //  8MB

  cvt_f32_bf16<<<4096, 256, 0, stream>>>(hid, hb);
  transpose_qkv<<<dim3(96, 64), 256, 0, stream>>>(wq, wk, wv, wqkvT);

  // fused QKV projection: [4096,2048] x [3072,2048]^T -> Qb | KVb
  gemm_bt1<<<768, 256, 0, stream>>>(hb, wqkvT, Qb, KVb, 4096, 3072, 2048);

  // RoPE table; K rotated in place. Q-RoPE fused into attn_kernel.
  rope_table<<<512, 256, 0, stream>>>(tab);
  rope_kernel<<<512, 256, 0, stream>>>(KVb, tab, 1024, 2, 1.0f);

  transpose_v<<<dim3(64, 16, 2), 256, 0, stream>>>(KVb, Vt);

  attn_kernel<<<dim3(16, 16, 2), 256, 0, stream>>>(Qb, KVb, Vt, tab, hb);

  // woT overwrites the table region -- safe only after attn has run.
  transpose_f32_bf16<<<dim3(64, 64), 256, 0, stream>>>(wo, woT, 2048, 2048);

  gemm_o64<<<512, 256, 0, stream>>>(hb, woT, out);
}

// Round 28
// 223.139 us; speedup vs baseline: 1.0078x; 1.0074x over previous
//
#include <hip/hip_runtime.h>

typedef unsigned short u16;
typedef unsigned int u32;
typedef __attribute__((ext_vector_type(8))) __bf16 bf16x8;
typedef __attribute__((ext_vector_type(8))) u16 u16x8;
typedef __attribute__((ext_vector_type(4))) float f32x4;

#define B_ 2
#define S_ 2048
#define H_ 2048
#define NH_ 16
#define NKV_ 4
#define HD_ 128
#define QSCALE 0.1275179064f  // log2(e)/sqrt(128) -> log2-domain scores

__device__ __forceinline__ u16 f2bf(float f) {
  return __builtin_bit_cast(u16, static_cast<__bf16>(f));
}
__device__ __forceinline__ float bf2f(u16 v) {
  return __builtin_bit_cast(float, (u32)v << 16);
}
__device__ __forceinline__ void gl2lds16(const void* g, void* l) {
  __builtin_amdgcn_global_load_lds((const __attribute__((address_space(1))) u32*)g,
                                   (__attribute__((address_space(3))) u32*)l, 16, 0, 0);
}
__device__ __forceinline__ f32x4 mfma16(bf16x8 a, bf16x8 b, f32x4 c) {
  return __builtin_amdgcn_mfma_f32_16x16x32_bf16(a, b, c, 0, 0, 0);
}

// ---------------- fused prologue: cvt(hidden) | transpose wq/wk/wv ----------
// blocks [0,4096):      hid f32 -> hb bf16 (8 elem/thread)
// blocks [4096,10240):  weight transpose tile (bx = t%96, by = t/96)
// (rope table NOT here: no alias-safe workspace exists before the QKV GEMM.)
__global__ __launch_bounds__(256) void prologue(const float* __restrict__ hid,
                                                const float* __restrict__ wq,
                                                const float* __restrict__ wk,
                                                const float* __restrict__ wv,
                                                u16* __restrict__ hb,
                                                u16* __restrict__ wqkvT) {
  const int bid = blockIdx.x;
  if (bid < 4096) {
    size_t i = ((size_t)bid * 256 + threadIdx.x) * 8;
    const float4* p = (const float4*)(hid + i);
    float4 a = p[0], b = p[1];
    u16x8 o;
    o[0] = f2bf(a.x); o[1] = f2bf(a.y); o[2] = f2bf(a.z); o[3] = f2bf(a.w);
    o[4] = f2bf(b.x); o[5] = f2bf(b.y); o[6] = f2bf(b.z); o[7] = f2bf(b.w);
    *(u16x8*)(hb + i) = o;
  } else {
    __shared__ float tl[32][33];
    int t = bid - 4096;
    int bx = t % 96, by = t / 96;
    int tx = threadIdx.x & 31, ty = threadIdx.x >> 5;
    int orow0 = bx * 32;
    const float* src;
    int scol0, C;
    if (orow0 < 2048)      { src = wq; scol0 = orow0;        C = 2048; }
    else if (orow0 < 2560) { src = wk; scol0 = orow0 - 2048; C = 512; }
    else                   { src = wv; scol0 = orow0 - 2560; C = 512; }
#pragma unroll
    for (int i = 0; i < 32; i += 8)
      tl[ty + i][tx] = src[(size_t)(by * 32 + ty + i) * C + scol0 + tx];
    __syncthreads();
#pragma unroll
    for (int i = 0; i < 32; i += 8)
      wqkvT[(size_t)(orow0 + ty + i) * 2048 + by * 32 + tx] = f2bf(tl[tx][ty + i]);
  }
}

// ---------------- RoPE cos/sin table: tab[s][i] = {cos,sin}(s * 10000^(-i/64))
// Launched AFTER the QKV GEMM; tab lives in the then-dead wqkvT region.
__global__ __launch_bounds__(256) void rope_table(float* __restrict__ tab) {
  int idx = blockIdx.x * 256 + threadIdx.x;  // 131072 = 2048 x 64
  int s = idx >> 6, i = idx & 63;
  float inv = exp2f((float)i * -0.20762050593045702f);
  float ang = (float)s * inv;
  tab[2 * idx] = cosf(ang);
  tab[2 * idx + 1] = sinf(ang);
}

// ---------------- transpose V part of KV buffer: bf16 -> Vt[b][512 d][2048 s] ----------------
__global__ __launch_bounds__(256) void transpose_v(const u16* __restrict__ kvb,
                                                   u16* __restrict__ vt) {
  __shared__ u16 tl[32][33];
  int sx = blockIdx.x, dx = blockIdx.y, b = blockIdx.z;
  int tx = threadIdx.x & 31, ty = threadIdx.x >> 5;
#pragma unroll
  for (int i = 0; i < 32; i += 8)
    tl[ty + i][tx] = kvb[(size_t)(b * S_ + sx * 32 + ty + i) * 1024 + 512 + dx * 32 + tx];
  __syncthreads();
#pragma unroll
  for (int i = 0; i < 32; i += 8)
    vt[(size_t)(b * 512 + dx * 32 + ty + i) * 2048 + sx * 32 + tx] = tl[tx][ty + i];
}

// ---------------- transpose fp32 [R][C] -> bf16 [C][R] (wo) ----------------
__global__ __launch_bounds__(256) void transpose_f32_bf16(const float* __restrict__ in,
                                                          u16* __restrict__ out,
                                                          int R, int C) {
  __shared__ float tl[32][33];
  int bx = blockIdx.x, by = blockIdx.y;
  int tx = threadIdx.x & 31, ty = threadIdx.x >> 5;
#pragma unroll
  for (int i = 0; i < 32; i += 8)
    tl[ty + i][tx] = in[(size_t)(by * 32 + ty + i) * C + bx * 32 + tx];
  __syncthreads();
#pragma unroll
  for (int i = 0; i < 32; i += 8)
    out[(size_t)(bx * 32 + ty + i) * R + by * 32 + tx] = f2bf(tl[tx][ty + i]);
}

// ---------------- RoPE in place on bf16 buffer (table-driven; K only) --------
__global__ __launch_bounds__(256) void rope_kernel(u16* __restrict__ buf,
                                                   const float* __restrict__ tab,
                                                   int rstride, int nhshift, float scale) {
  int idx = blockIdx.x * 256 + threadIdx.x;
  int grp = idx & 7;
  int h = (idx >> 3) & ((1 << nhshift) - 1);
  int tok = idx >> (3 + nhshift);
  int s = tok & (S_ - 1);
  u16* p = buf + (size_t)tok * rstride + (h << 7) + grp * 8;
  const float2* tp = (const float2*)tab + (size_t)s * 64 + grp * 8;
  u16x8 lo = *(u16x8*)p;
  u16x8 hi = *(u16x8*)(p + 64);
  u16x8 olo, ohi;
#pragma unroll
  for (int j = 0; j < 8; j++) {
    float2 cs = tp[j];
    float c = cs.x * scale, sn = cs.y * scale;
    float xl = bf2f(lo[j]), xh = bf2f(hi[j]);
    olo[j] = f2bf(xl * c - xh * sn);
    ohi[j] = f2bf(xh * c + xl * sn);
  }
  *(u16x8*)p = olo;
  *(u16x8*)(p + 64) = ohi;
}

// ---------------- bf16 GEMM (QKV): C = A[M,K] * BT[N,K]^T, BK=32 ------------
__global__ __launch_bounds__(256) void gemm_bt1(const u16* __restrict__ A,
                                                const u16* __restrict__ BT,
                                                u16* __restrict__ Qb,
                                                u16* __restrict__ KVb,
                                                int M, int N, int K) {
  __shared__ u16 As[2 * 128 * 32];  // 16KB
  __shared__ u16 Bs[2 * 128 * 32];  // 16KB
  const int Mt = M >> 7;
  const int nwg = gridDim.x;
  int wg = (blockIdx.x & 7) * (nwg >> 3) + (blockIdx.x >> 3);  // XCD swizzle
  int tm = wg % Mt, tn = wg / Mt;
  const size_t m0 = (size_t)tm << 7, n0 = (size_t)tn << 7;
  const int tid = threadIdx.x;
  const int w = tid >> 6, lane = tid & 63;
  const int g = lane >> 4, l15 = lane & 15;
  const int wr = w >> 1, wc = w & 1;

  const int r0 = tid >> 2, s0 = tid & 3;
  const int r1 = (tid + 256) >> 2, s1 = (tid + 256) & 3;
  const u16* Ar0 = A + (m0 + r0) * K + s0 * 8;
  const u16* Ar1 = A + (m0 + r1) * K + s1 * 8;
  const u16* Br0 = BT + (n0 + r0) * K + s0 * 8;
  const u16* Br1 = BT + (n0 + r1) * K + s1 * 8;

  const f32x4 Z4 = {0.f, 0.f, 0.f, 0.f};
  f32x4 acc[4][4];
#pragma unroll
  for (int m = 0; m < 4; m++)
#pragma unroll
    for (int n = 0; n < 4; n++) acc[m][n] = Z4;

  gl2lds16(Ar0, &As[w * 512]);
  gl2lds16(Ar1, &As[w * 512 + 2048]);
  gl2lds16(Br0, &Bs[w * 512]);
  gl2lds16(Br1, &Bs[w * 512 + 2048]);

  const int nk = K >> 5;
  int cur = 0;
  for (int t = 0; t < nk; ++t) {
    if (t + 1 < nk) {
      const int k0 = (t + 1) << 5;
      const int nb = (cur ^ 1) << 12;
      gl2lds16(Ar0 + k0, &As[nb + w * 512]);
      gl2lds16(Ar1 + k0, &As[nb + w * 512 + 2048]);
      gl2lds16(Br0 + k0, &Bs[nb + w * 512]);
      gl2lds16(Br1 + k0, &Bs[nb + w * 512 + 2048]);
      asm volatile("s_waitcnt vmcnt(4)" ::: "memory");
    } else {
      asm volatile("s_waitcnt vmcnt(0)" ::: "memory");
    }
    __builtin_amdgcn_sched_barrier(0);
    __builtin_amdgcn_s_barrier();
    __builtin_amdgcn_sched_barrier(0);
    const int cb = cur << 12;
    bf16x8 af[4], bfr[4];
#pragma unroll
    for (int m = 0; m < 4; m++)
      af[m] = *(const bf16x8*)&As[cb + (wr * 64 + m * 16 + l15) * 32 + g * 8];
#pragma unroll
    for (int n = 0; n < 4; n++)
      bfr[n] = *(const bf16x8*)&Bs[cb + (wc * 64 + n * 16 + l15) * 32 + g * 8];
#pragma unroll
    for (int m = 0; m < 4; m++)
#pragma unroll
      for (int n = 0; n < 4; n++) acc[m][n] = mfma16(af[m], bfr[n], acc[m][n]);
    __builtin_amdgcn_sched_barrier(0);
    __builtin_amdgcn_s_barrier();
    __builtin_amdgcn_sched_barrier(0);
    cur ^= 1;
  }

  u16* C;
  size_t cs, cbase;
  if (n0 < 2048) { C = Qb; cs = 2048; cbase = n0; }
  else           { C = KVb; cs = 1024; cbase = n0 - 2048; }
#pragma unroll
  for (int m = 0; m < 4; m++)
#pragma unroll
    for (int n = 0; n < 4; n++)
#pragma unroll
      for (int r = 0; r < 4; r++) {
        size_t row = m0 + wr * 64 + m * 16 + g * 4 + r;
        C[row * cs + cbase + wc * 64 + n * 16 + l15] = f2bf(acc[m][n][r]);
      }
}

// ---------------- O-projection GEMM: BK=64, swizzled LDS, f32 out -----------
__global__ __launch_bounds__(256) void gemm_o64(const u16* __restrict__ A,
                                                const u16* __restrict__ BT,
                                                float* __restrict__ C) {
  const int K = 2048, N = 2048;
  __shared__ u16 As[2 * 128 * 64];  // 32KB
  __shared__ u16 Bs[2 * 128 * 64];  // 32KB
  const int Mt = 32;
  const int nwg = gridDim.x;  // 512
  int wg = (blockIdx.x & 7) * (nwg >> 3) + (blockIdx.x >> 3);  // XCD swizzle
  int tm = wg % Mt, tn = wg / Mt;
  const size_t m0 = (size_t)tm << 7, n0 = (size_t)tn << 7;
  const int tid = threadIdx.x;
  const int w = tid >> 6, lane = tid & 63;
  const int g = lane >> 4, l15 = lane & 15;
  const int wr = w >> 1, wc = w & 1;

  size_t aoff[4], boff[4];
#pragma unroll
  for (int ro = 0; ro < 4; ++ro) {
    int c = ro * 256 + tid;
    int row = c >> 3, seg = c & 7;
    aoff[ro] = (m0 + row) * (size_t)K + 8 * (seg ^ (row & 7));
    boff[ro] = (n0 + row) * (size_t)K + 8 * (seg ^ (row & 7));
  }

  const f32x4 Z4 = {0.f, 0.f, 0.f, 0.f};
  f32x4 acc[4][4];
#pragma unroll
  for (int m = 0; m < 4; m++)
#pragma unroll
    for (int n = 0; n < 4; n++) acc[m][n] = Z4;

#pragma unroll
  for (int ro = 0; ro < 4; ++ro) {
    gl2lds16(A + aoff[ro], &As[ro * 2048 + w * 512]);
    gl2lds16(BT + boff[ro], &Bs[ro * 2048 + w * 512]);
  }

  const int nk = K >> 6;  // 32
  int cur = 0;
  for (int t = 0; t < nk; ++t) {
    if (t + 1 < nk) {
      const int k0 = (t + 1) << 6;
      const int nb = (cur ^ 1) << 13;
#pragma unroll
      for (int ro = 0; ro < 4; ++ro) {
        gl2lds16(A + k0 + aoff[ro], &As[nb + ro * 2048 + w * 512]);
        gl2lds16(BT + k0 + boff[ro], &Bs[nb + ro * 2048 + w * 512]);
      }
      asm volatile("s_waitcnt vmcnt(8)" ::: "memory");
    } else {
      asm volatile("s_waitcnt vmcnt(0)" ::: "memory");
    }
    __builtin_amdgcn_sched_barrier(0);
    __builtin_amdgcn_s_barrier();
    __builtin_amdgcn_sched_barrier(0);
    const int cb = cur << 13;
    bf16x8 af[2][4], bfr[2][4];
#pragma unroll
    for (int kk = 0; kk < 2; ++kk) {
#pragma unroll
      for (int m = 0; m < 4; m++)
        af[kk][m] = *(const bf16x8*)&As[cb + (wr * 64 + m * 16 + l15) * 64 +
                                       ((kk * 4 + g) ^ (l15 & 7)) * 8];
#pragma unroll
      for (int n = 0; n < 4; n++)
        bfr[kk][n] = *(const bf16x8*)&Bs[cb + (wc * 64 + n * 16 + l15) * 64 +
                                        ((kk * 4 + g) ^ (l15 & 7)) * 8];
    }
#pragma unroll
    for (int kk = 0; kk < 2; ++kk)
#pragma unroll
      for (int m = 0; m < 4; m++)
#pragma unroll
        for (int n = 0; n < 4; n++)
          acc[m][n] = mfma16(af[kk][m], bfr[kk][n], acc[m][n]);
    __builtin_amdgcn_sched_barrier(0);
    __builtin_amdgcn_s_barrier();
    __builtin_amdgcn_sched_barrier(0);
    cur ^= 1;
  }

#pragma unroll
  for (int m = 0; m < 4; m++)
#pragma unroll
    for (int n = 0; n < 4; n++)
#pragma unroll
      for (int r = 0; r < 4; r++) {
        size_t row = m0 + wr * 64 + m * 16 + g * 4 + r;
        size_t col = n0 + wc * 64 + n * 16 + l15;
        C[row * (size_t)N + col] = acc[m][n][r];
      }
}

// ---------------- flash attention (R15 structure + fused Q-RoPE) ------------
// Qb: [B*S, 2048] bf16 RAW; KVb: [B*S, 1024] bf16 (K RoPE'd | V);
// Vt: [B*512][2048] bf16; Ob: bf16. Q-RoPE fused at Q load (freq = ds*32+g*8+j).
__global__ __launch_bounds__(256) void attn_kernel(const u16* __restrict__ Qb,
                                                   const u16* __restrict__ KVb,
                                                   const u16* __restrict__ Vt,
                                                   const float* __restrict__ tab,
                                                   u16* __restrict__ Ob) {
  __shared__ u16 Ks[2][64 * 128];
  __shared__ u16 Vs[2][128 * 64];
  __shared__ u16 Ps[4][16 * 72];
  const int pair = blockIdx.x, h = blockIdx.y, b = blockIdx.z;
  const int kvh = h >> 2;
  const int tid = threadIdx.x, w = tid >> 6, lane = tid & 63;
  const int g = lane >> 4, l15 = lane & 15;
  const f32x4 Z4 = {0.f, 0.f, 0.f, 0.f};
  u16x8 oneu;
#pragma unroll
  for (int j = 0; j < 8; j++) oneu[j] = 0x3f80;
  const bf16x8 ones = __builtin_bit_cast(bf16x8, oneu);

  const u16* Kbase = KVb + (size_t)b * S_ * 1024 + kvh * 128;
  const u16* Vbase = Vt + (size_t)(b * NKV_ + kvh) * HD_ * 2048;

  for (int half = 0; half < 2; ++half) {
    const int qt = half ? pair : 31 - pair;
    const int qrow0 = qt * 64 + w * 16;

    bf16x8 qf[4];
    const u16* qp = Qb + (size_t)(b * S_ + qrow0 + l15) * 2048 + h * 128;
#pragma unroll
    for (int ds = 0; ds < 4; ds++) qf[ds] = *(const bf16x8*)(qp + ds * 32 + g * 8);
    // fused Q-RoPE (+ QSCALE fold): rotate (d, d+64) pairs in-register
    {
      const float2* tq = (const float2*)tab + (size_t)(qrow0 + l15) * 64 + g * 8;
#pragma unroll
      for (int ds = 0; ds < 2; ds++) {
        u16x8 a = __builtin_bit_cast(u16x8, qf[ds]);
        u16x8 bb = __builtin_bit_cast(u16x8, qf[ds + 2]);
#pragma unroll
        for (int j = 0; j < 8; j++) {
          float2 cs = tq[ds * 32 + j];  // freq idx = ds*32 + g*8 + j
          float c = cs.x * QSCALE, sn = cs.y * QSCALE;
          float lo = bf2f(a[j]), hi = bf2f(bb[j]);
          a[j] = f2bf(lo * c - hi * sn);
          bb[j] = f2bf(hi * c + lo * sn);
        }
        qf[ds] = __builtin_bit_cast(bf16x8, a);
        qf[ds + 2] = __builtin_bit_cast(bf16x8, bb);
      }
    }

    float m_r[4], l_r[4];
    f32x4 oa[8];
#pragma unroll
    for (int r = 0; r < 4; r++) { m_r[r] = -1e30f; l_r[r] = 0.f; }
#pragma unroll
    for (int n = 0; n < 8; n++) oa[n] = Z4;

    const int nt = qt + 1;
#pragma unroll
    for (int ro = 0; ro < 4; ++ro) {
      int c = ro * 256 + tid;
      int kv = c >> 4, p = c & 15;
      gl2lds16(Kbase + (size_t)kv * 1024 + 8 * (p ^ (kv & 15)), &Ks[0][ro * 2048 + w * 512]);
      int d = c >> 3, p2 = c & 7;
      gl2lds16(Vbase + (size_t)d * 2048 + 8 * (p2 ^ (d & 7)), &Vs[0][ro * 2048 + w * 512]);
    }
    __syncthreads();
    int cur = 0;

    for (int t = 0; t < nt; ++t) {
      const int kv0 = t * 64;
      if (t + 1 < nt) {
        const int nkv0 = kv0 + 64;
#pragma unroll
        for (int ro = 0; ro < 4; ++ro) {
          int c = ro * 256 + tid;
          int kv = c >> 4, p = c & 15;
          gl2lds16(Kbase + (size_t)(nkv0 + kv) * 1024 + 8 * (p ^ (kv & 15)),
                   &Ks[cur ^ 1][ro * 2048 + w * 512]);
          int d = c >> 3, p2 = c & 7;
          gl2lds16(Vbase + (size_t)d * 2048 + nkv0 + 8 * (p2 ^ (d & 7)),
                   &Vs[cur ^ 1][ro * 2048 + w * 512]);
        }
      }

      f32x4 sa[4];
#pragma unroll
      for (int c16 = 0; c16 < 4; c16++) sa[c16] = Z4;
      __builtin_amdgcn_s_setprio(1);
#pragma unroll
      for (int ds = 0; ds < 4; ++ds) {
#pragma unroll
        for (int c16 = 0; c16 < 4; ++c16) {
          bf16x8 kf = *(const bf16x8*)&Ks[cur][(c16 * 16 + l15) * 128 + ((ds * 4 + g) ^ l15) * 8];
          sa[c16] = mfma16(qf[ds], kf, sa[c16]);
        }
      }
      __builtin_amdgcn_s_setprio(0);

      if (kv0 + 63 > qrow0) {
#pragma unroll
        for (int c16 = 0; c16 < 4; c16++)
#pragma unroll
          for (int r = 0; r < 4; r++) {
            if (kv0 + c16 * 16 + l15 > qrow0 + g * 4 + r) sa[c16][r] = -1e30f;
          }
      }

      float lmax[4];
#pragma unroll
      for (int r = 0; r < 4; r++)
        lmax[r] = fmaxf(fmaxf(sa[0][r], sa[1][r]), fmaxf(sa[2][r], sa[3][r]));
      bool need = (lmax[0] > m_r[0] + 11.5415603f) || (lmax[1] > m_r[1] + 11.5415603f) ||
                  (lmax[2] > m_r[2] + 11.5415603f) || (lmax[3] > m_r[3] + 11.5415603f);
      if (__any(need)) {
        float pm[4];
#pragma unroll
        for (int r = 0; r < 4; r++) pm[r] = lmax[r];
#pragma unroll
        for (int off = 1; off < 16; off <<= 1)
#pragma unroll
          for (int r = 0; r < 4; r++) pm[r] = fmaxf(pm[r], __shfl_xor(pm[r], off));
#pragma unroll
        for (int r = 0; r < 4; r++) {
          float mn = fmaxf(m_r[r], pm[r]);
          float corr = exp2f(m_r[r] - mn);
          m_r[r] = mn;
          l_r[r] *= corr;
#pragma unroll
          for (int n = 0; n < 8; n++) oa[n][r] *= corr;
        }
      }

#pragma unroll
      for (int c16 = 0; c16 < 4; c16++)
#pragma unroll
        for (int r = 0; r < 4; r++)
          Ps[w][(g * 4 + r) * 72 + c16 * 16 + l15] =
              f2bf(exp2f(sa[c16][r] - m_r[r]));
      asm volatile("s_waitcnt lgkmcnt(0)" ::: "memory");
      __builtin_amdgcn_sched_barrier(0);

      f32x4 srow = Z4;
      __builtin_amdgcn_s_setprio(1);
#pragma unroll
      for (int ks = 0; ks < 2; ++ks) {
        bf16x8 pa = *(const bf16x8*)&Ps[w][l15 * 72 + ks * 32 + g * 8];
        srow = mfma16(pa, ones, srow);
#pragma unroll
        for (int n = 0; n < 8; n++) {
          bf16x8 vf = *(const bf16x8*)&Vs[cur][(n * 16 + l15) * 64 + (((ks * 4 + g) ^ (l15 & 7))) * 8];
          oa[n] = mfma16(pa, vf, oa[n]);
        }
      }
      __builtin_amdgcn_s_setprio(0);
#pragma unroll
      for (int r = 0; r < 4; r++) l_r[r] += srow[r];

      __syncthreads();
      cur ^= 1;
    }

    float inv[4];
#pragma unroll
    for (int r = 0; r < 4; r++) inv[r] = 1.0f / l_r[r];
#pragma unroll
    for (int n = 0; n < 8; n++)
#pragma unroll
      for (int r = 0; r < 4; r++) {
        size_t row = (size_t)b * S_ + qrow0 + g * 4 + r;
        Ob[row * 2048 + h * 128 + n * 16 + l15] = f2bf(oa[n][r] * inv[r]);
      }
  }
}

extern "C" void kernel_launch(void* const* d_in, const int* in_sizes, int n_in,
                              void* d_out, int out_size, void* d_ws, size_t ws_size,
                              hipStream_t stream) {
  const float* hid = (const float*)d_in[0];
  // d_in[1] = attention_mask: exactly causal; implemented directly in attn_kernel.
  const float* wq = (const float*)d_in[2];
  const float* wk = (const float*)d_in[3];
  const float* wv = (const float*)d_in[4];
  const float* wo = (const float*)d_in[5];
  float* out = (float*)d_out;
  char* ws = (char*)d_ws;

  // workspace layout (52 MB total)
  u16* hb     = (u16*)(ws);                   // 16MB: hidden bf16 -> later attn output
  u16* wqkvT  = (u16*)(ws + (16u << 20));     // 12MB: [wqT;wkT;wvT] (3072 x 2048)
  u16* Vt     = (u16*)(ws + (16u << 20));     //  4MB: reuse after QKV GEMM
  float* tab  = (float*)(ws + (20u << 20));   //  1MB: rope table, written AFTER QKV GEMM
  u16* woT    = (u16*)(ws + (20u << 20));     //  8MB: written AFTER attn (overwrites tab)
  u16* Qb     = (u16*)(ws + (28u << 20));     // 16MB
  u16* KVb    = (u16*)(ws + (44u << 20));     //  8MB

  // fused prologue: cvt(hidden) + weight transpose (alias-safe; no tab here)
  prologue<<<10240, 256, 0, stream>>>(hid, wq, wk, wv, hb, wqkvT);

  // fused QKV projection: [4096,2048] x [3072,2048]^T -> Qb | KVb
  gemm_bt1<<<768, 256, 0, stream>>>(hb, wqkvT, Qb, KVb, 4096, 3072, 2048);

  // rope table into dead wqkvT region (safe: QKV GEMM has consumed wqkvT)
  rope_table<<<512, 256, 0, stream>>>(tab);
  rope_kernel<<<512, 256, 0, stream>>>(KVb, tab, 1024, 2, 1.0f);

  transpose_v<<<dim3(64, 16, 2), 256, 0, stream>>>(KVb, Vt);

  attn_kernel<<<dim3(16, 16, 2), 256, 0, stream>>>(Qb, KVb, Vt, tab, hb);

  // woT at ws+20M overwrites tab -- safe only after attn has run.
  transpose_f32_bf16<<<dim3(64, 64), 256, 0, stream>>>(wo, woT, 2048, 2048);

  gemm_o64<<<512, 256, 0, stream>>>(hb, woT, out);
}

// Round 29
// 219.987 us; speedup vs baseline: 1.0223x; 1.0143x over previous
//
#include <hip/hip_runtime.h>

typedef unsigned short u16;
typedef unsigned int u32;
typedef __attribute__((ext_vector_type(8))) __bf16 bf16x8;
typedef __attribute__((ext_vector_type(8))) u16 u16x8;
typedef __attribute__((ext_vector_type(4))) float f32x4;

#define B_ 2
#define S_ 2048
#define H_ 2048
#define NH_ 16
#define NKV_ 4
#define HD_ 128
#define QSCALE 0.1275179064f  // log2(e)/sqrt(128) -> log2-domain scores

__device__ __forceinline__ u16 f2bf(float f) {
  return __builtin_bit_cast(u16, static_cast<__bf16>(f));
}
__device__ __forceinline__ float bf2f(u16 v) {
  return __builtin_bit_cast(float, (u32)v << 16);
}
__device__ __forceinline__ void gl2lds16(const void* g, void* l) {
  __builtin_amdgcn_global_load_lds((const __attribute__((address_space(1))) u32*)g,
                                   (__attribute__((address_space(3))) u32*)l, 16, 0, 0);
}
__device__ __forceinline__ f32x4 mfma16(bf16x8 a, bf16x8 b, f32x4 c) {
  return __builtin_amdgcn_mfma_f32_16x16x32_bf16(a, b, c, 0, 0, 0);
}

// ---------------- fused prologue: cvt(hidden) | transpose wq/wk/wv ----------
// blocks [0,4096):      hid f32 -> hb bf16 (8 elem/thread)
// blocks [4096,10240):  weight transpose tile (bx = t%96, by = t/96)
__global__ __launch_bounds__(256) void prologue(const float* __restrict__ hid,
                                                const float* __restrict__ wq,
                                                const float* __restrict__ wk,
                                                const float* __restrict__ wv,
                                                u16* __restrict__ hb,
                                                u16* __restrict__ wqkvT) {
  const int bid = blockIdx.x;
  if (bid < 4096) {
    size_t i = ((size_t)bid * 256 + threadIdx.x) * 8;
    const float4* p = (const float4*)(hid + i);
    float4 a = p[0], b = p[1];
    u16x8 o;
    o[0] = f2bf(a.x); o[1] = f2bf(a.y); o[2] = f2bf(a.z); o[3] = f2bf(a.w);
    o[4] = f2bf(b.x); o[5] = f2bf(b.y); o[6] = f2bf(b.z); o[7] = f2bf(b.w);
    *(u16x8*)(hb + i) = o;
  } else {
    __shared__ float tl[32][33];
    int t = bid - 4096;
    int bx = t % 96, by = t / 96;
    int tx = threadIdx.x & 31, ty = threadIdx.x >> 5;
    int orow0 = bx * 32;
    const float* src;
    int scol0, C;
    if (orow0 < 2048)      { src = wq; scol0 = orow0;        C = 2048; }
    else if (orow0 < 2560) { src = wk; scol0 = orow0 - 2048; C = 512; }
    else                   { src = wv; scol0 = orow0 - 2560; C = 512; }
#pragma unroll
    for (int i = 0; i < 32; i += 8)
      tl[ty + i][tx] = src[(size_t)(by * 32 + ty + i) * C + scol0 + tx];
    __syncthreads();
#pragma unroll
    for (int i = 0; i < 32; i += 8)
      wqkvT[(size_t)(orow0 + ty + i) * 2048 + by * 32 + tx] = f2bf(tl[tx][ty + i]);
  }
}

// ---------------- fused midpass (after QKV GEMM, before attn) ---------------
// blocks [0,512):     rope table -> tab (read only by the LATER attn kernel)
// blocks [512,1024):  K-RoPE in place on KVb, INLINE trig (no tab dependency)
// blocks [1024,3072): V transpose KVb -> Vt (disjoint cols from K-RoPE)
__global__ __launch_bounds__(256) void midpass(u16* __restrict__ kvb,
                                               u16* __restrict__ vt,
                                               float* __restrict__ tab) {
  const int bid = blockIdx.x;
  if (bid < 512) {
    int idx = bid * 256 + threadIdx.x;  // 131072 = 2048 x 64
    int s = idx >> 6, i = idx & 63;
    float inv = exp2f((float)i * -0.20762050593045702f);
    float ang = (float)s * inv;
    tab[2 * idx] = cosf(ang);
    tab[2 * idx + 1] = sinf(ang);
  } else if (bid < 1024) {
    int idx = (bid - 512) * 256 + threadIdx.x;
    int grp = idx & 7;
    int h = (idx >> 3) & 3;       // NKV = 4
    int tok = idx >> 5;
    int s = tok & (S_ - 1);
    u16* p = kvb + (size_t)tok * 1024 + (h << 7) + grp * 8;
    u16x8 lo = *(u16x8*)p;
    u16x8 hi = *(u16x8*)(p + 64);
    u16x8 olo, ohi;
#pragma unroll
    for (int j = 0; j < 8; j++) {
      int i = grp * 8 + j;
      float inv = exp2f((float)i * -0.20762050593045702f);
      float ang = (float)s * inv;
      float c = cosf(ang), sn = sinf(ang);
      float xl = bf2f(lo[j]), xh = bf2f(hi[j]);
      olo[j] = f2bf(xl * c - xh * sn);
      ohi[j] = f2bf(xh * c + xl * sn);
    }
    *(u16x8*)p = olo;
    *(u16x8*)(p + 64) = ohi;
  } else {
    __shared__ u16 tl[32][33];
    int t = bid - 1024;           // 2048 tiles = 64 x 16 x 2
    int sx = t & 63, dx = (t >> 6) & 15, b = t >> 10;
    int tx = threadIdx.x & 31, ty = threadIdx.x >> 5;
#pragma unroll
    for (int i = 0; i < 32; i += 8)
      tl[ty + i][tx] = kvb[(size_t)(b * S_ + sx * 32 + ty + i) * 1024 + 512 + dx * 32 + tx];
    __syncthreads();
#pragma unroll
    for (int i = 0; i < 32; i += 8)
      vt[(size_t)(b * 512 + dx * 32 + ty + i) * 2048 + sx * 32 + tx] = tl[tx][ty + i];
  }
}

// ---------------- transpose fp32 [R][C] -> bf16 [C][R] (wo) ----------------
__global__ __launch_bounds__(256) void transpose_f32_bf16(const float* __restrict__ in,
                                                          u16* __restrict__ out,
                                                          int R, int C) {
  __shared__ float tl[32][33];
  int bx = blockIdx.x, by = blockIdx.y;
  int tx = threadIdx.x & 31, ty = threadIdx.x >> 5;
#pragma unroll
  for (int i = 0; i < 32; i += 8)
    tl[ty + i][tx] = in[(size_t)(by * 32 + ty + i) * C + bx * 32 + tx];
  __syncthreads();
#pragma unroll
  for (int i = 0; i < 32; i += 8)
    out[(size_t)(bx * 32 + ty + i) * R + by * 32 + tx] = f2bf(tl[tx][ty + i]);
}

// ---------------- bf16 GEMM (QKV): C = A[M,K] * BT[N,K]^T, BK=32 ------------
__global__ __launch_bounds__(256) void gemm_bt1(const u16* __restrict__ A,
                                                const u16* __restrict__ BT,
                                                u16* __restrict__ Qb,
                                                u16* __restrict__ KVb,
                                                int M, int N, int K) {
  __shared__ u16 As[2 * 128 * 32];  // 16KB
  __shared__ u16 Bs[2 * 128 * 32];  // 16KB
  const int Mt = M >> 7;
  const int nwg = gridDim.x;
  int wg = (blockIdx.x & 7) * (nwg >> 3) + (blockIdx.x >> 3);  // XCD swizzle
  int tm = wg % Mt, tn = wg / Mt;
  const size_t m0 = (size_t)tm << 7, n0 = (size_t)tn << 7;
  const int tid = threadIdx.x;
  const int w = tid >> 6, lane = tid & 63;
  const int g = lane >> 4, l15 = lane & 15;
  const int wr = w >> 1, wc = w & 1;

  const int r0 = tid >> 2, s0 = tid & 3;
  const int r1 = (tid + 256) >> 2, s1 = (tid + 256) & 3;
  const u16* Ar0 = A + (m0 + r0) * K + s0 * 8;
  const u16* Ar1 = A + (m0 + r1) * K + s1 * 8;
  const u16* Br0 = BT + (n0 + r0) * K + s0 * 8;
  const u16* Br1 = BT + (n0 + r1) * K + s1 * 8;

  const f32x4 Z4 = {0.f, 0.f, 0.f, 0.f};
  f32x4 acc[4][4];
#pragma unroll
  for (int m = 0; m < 4; m++)
#pragma unroll
    for (int n = 0; n < 4; n++) acc[m][n] = Z4;

  gl2lds16(Ar0, &As[w * 512]);
  gl2lds16(Ar1, &As[w * 512 + 2048]);
  gl2lds16(Br0, &Bs[w * 512]);
  gl2lds16(Br1, &Bs[w * 512 + 2048]);

  const int nk = K >> 5;
  int cur = 0;
  for (int t = 0; t < nk; ++t) {
    if (t + 1 < nk) {
      const int k0 = (t + 1) << 5;
      const int nb = (cur ^ 1) << 12;
      gl2lds16(Ar0 + k0, &As[nb + w * 512]);
      gl2lds16(Ar1 + k0, &As[nb + w * 512 + 2048]);
      gl2lds16(Br0 + k0, &Bs[nb + w * 512]);
      gl2lds16(Br1 + k0, &Bs[nb + w * 512 + 2048]);
      asm volatile("s_waitcnt vmcnt(4)" ::: "memory");
    } else {
      asm volatile("s_waitcnt vmcnt(0)" ::: "memory");
    }
    __builtin_amdgcn_sched_barrier(0);
    __builtin_amdgcn_s_barrier();
    __builtin_amdgcn_sched_barrier(0);
    const int cb = cur << 12;
    bf16x8 af[4], bfr[4];
#pragma unroll
    for (int m = 0; m < 4; m++)
      af[m] = *(const bf16x8*)&As[cb + (wr * 64 + m * 16 + l15) * 32 + g * 8];
#pragma unroll
    for (int n = 0; n < 4; n++)
      bfr[n] = *(const bf16x8*)&Bs[cb + (wc * 64 + n * 16 + l15) * 32 + g * 8];
#pragma unroll
    for (int m = 0; m < 4; m++)
#pragma unroll
      for (int n = 0; n < 4; n++) acc[m][n] = mfma16(af[m], bfr[n], acc[m][n]);
    __builtin_amdgcn_sched_barrier(0);
    __builtin_amdgcn_s_barrier();
    __builtin_amdgcn_sched_barrier(0);
    cur ^= 1;
  }

  u16* C;
  size_t cs, cbase;
  if (n0 < 2048) { C = Qb; cs = 2048; cbase = n0; }
  else           { C = KVb; cs = 1024; cbase = n0 - 2048; }
#pragma unroll
  for (int m = 0; m < 4; m++)
#pragma unroll
    for (int n = 0; n < 4; n++)
#pragma unroll
      for (int r = 0; r < 4; r++) {
        size_t row = m0 + wr * 64 + m * 16 + g * 4 + r;
        C[row * cs + cbase + wc * 64 + n * 16 + l15] = f2bf(acc[m][n][r]);
      }
}

// ---------------- O-projection GEMM: BK=64, swizzled LDS, f32 out -----------
__global__ __launch_bounds__(256) void gemm_o64(const u16* __restrict__ A,
                                                const u16* __restrict__ BT,
                                                float* __restrict__ C) {
  const int K = 2048, N = 2048;
  __shared__ u16 As[2 * 128 * 64];  // 32KB
  __shared__ u16 Bs[2 * 128 * 64];  // 32KB
  const int Mt = 32;
  const int nwg = gridDim.x;  // 512
  int wg = (blockIdx.x & 7) * (nwg >> 3) + (blockIdx.x >> 3);  // XCD swizzle
  int tm = wg % Mt, tn = wg / Mt;
  const size_t m0 = (size_t)tm << 7, n0 = (size_t)tn << 7;
  const int tid = threadIdx.x;
  const int w = tid >> 6, lane = tid & 63;
  const int g = lane >> 4, l15 = lane & 15;
  const int wr = w >> 1, wc = w & 1;

  size_t aoff[4], boff[4];
#pragma unroll
  for (int ro = 0; ro < 4; ++ro) {
    int c = ro * 256 + tid;
    int row = c >> 3, seg = c & 7;
    aoff[ro] = (m0 + row) * (size_t)K + 8 * (seg ^ (row & 7));
    boff[ro] = (n0 + row) * (size_t)K + 8 * (seg ^ (row & 7));
  }

  const f32x4 Z4 = {0.f, 0.f, 0.f, 0.f};
  f32x4 acc[4][4];
#pragma unroll
  for (int m = 0; m < 4; m++)
#pragma unroll
    for (int n = 0; n < 4; n++) acc[m][n] = Z4;

#pragma unroll
  for (int ro = 0; ro < 4; ++ro) {
    gl2lds16(A + aoff[ro], &As[ro * 2048 + w * 512]);
    gl2lds16(BT + boff[ro], &Bs[ro * 2048 + w * 512]);
  }

  const int nk = K >> 6;  // 32
  int cur = 0;
  for (int t = 0; t < nk; ++t) {
    if (t + 1 < nk) {
      const int k0 = (t + 1) << 6;
      const int nb = (cur ^ 1) << 13;
#pragma unroll
      for (int ro = 0; ro < 4; ++ro) {
        gl2lds16(A + k0 + aoff[ro], &As[nb + ro * 2048 + w * 512]);
        gl2lds16(BT + k0 + boff[ro], &Bs[nb + ro * 2048 + w * 512]);
      }
      asm volatile("s_waitcnt vmcnt(8)" ::: "memory");
    } else {
      asm volatile("s_waitcnt vmcnt(0)" ::: "memory");
    }
    __builtin_amdgcn_sched_barrier(0);
    __builtin_amdgcn_s_barrier();
    __builtin_amdgcn_sched_barrier(0);
    const int cb = cur << 13;
    bf16x8 af[2][4], bfr[2][4];
#pragma unroll
    for (int kk = 0; kk < 2; ++kk) {
#pragma unroll
      for (int m = 0; m < 4; m++)
        af[kk][m] = *(const bf16x8*)&As[cb + (wr * 64 + m * 16 + l15) * 64 +
                                       ((kk * 4 + g) ^ (l15 & 7)) * 8];
#pragma unroll
      for (int n = 0; n < 4; n++)
        bfr[kk][n] = *(const bf16x8*)&Bs[cb + (wc * 64 + n * 16 + l15) * 64 +
                                        ((kk * 4 + g) ^ (l15 & 7)) * 8];
    }
#pragma unroll
    for (int kk = 0; kk < 2; ++kk)
#pragma unroll
      for (int m = 0; m < 4; m++)
#pragma unroll
        for (int n = 0; n < 4; n++)
          acc[m][n] = mfma16(af[kk][m], bfr[kk][n], acc[m][n]);
    __builtin_amdgcn_sched_barrier(0);
    __builtin_amdgcn_s_barrier();
    __builtin_amdgcn_sched_barrier(0);
    cur ^= 1;
  }

#pragma unroll
  for (int m = 0; m < 4; m++)
#pragma unroll
    for (int n = 0; n < 4; n++)
#pragma unroll
      for (int r = 0; r < 4; r++) {
        size_t row = m0 + wr * 64 + m * 16 + g * 4 + r;
        size_t col = n0 + wc * 64 + n * 16 + l15;
        C[row * (size_t)N + col] = acc[m][n][r];
      }
}

// ---------------- flash attention (R15 structure + fused Q-RoPE) ------------
// Qb: [B*S, 2048] bf16 RAW; KVb: [B*S, 1024] bf16 (K RoPE'd | V);
// Vt: [B*512][2048] bf16; Ob: bf16. Q-RoPE fused at Q load (freq = ds*32+g*8+j).
__global__ __launch_bounds__(256) void attn_kernel(const u16* __restrict__ Qb,
                                                   const u16* __restrict__ KVb,
                                                   const u16* __restrict__ Vt,
                                                   const float* __restrict__ tab,
                                                   u16* __restrict__ Ob) {
  __shared__ u16 Ks[2][64 * 128];
  __shared__ u16 Vs[2][128 * 64];
  __shared__ u16 Ps[4][16 * 72];
  const int pair = blockIdx.x, h = blockIdx.y, b = blockIdx.z;
  const int kvh = h >> 2;
  const int tid = threadIdx.x, w = tid >> 6, lane = tid & 63;
  const int g = lane >> 4, l15 = lane & 15;
  const f32x4 Z4 = {0.f, 0.f, 0.f, 0.f};
  u16x8 oneu;
#pragma unroll
  for (int j = 0; j < 8; j++) oneu[j] = 0x3f80;
  const bf16x8 ones = __builtin_bit_cast(bf16x8, oneu);

  const u16* Kbase = KVb + (size_t)b * S_ * 1024 + kvh * 128;
  const u16* Vbase = Vt + (size_t)(b * NKV_ + kvh) * HD_ * 2048;

  for (int half = 0; half < 2; ++half) {
    const int qt = half ? pair : 31 - pair;
    const int qrow0 = qt * 64 + w * 16;

    bf16x8 qf[4];
    const u16* qp = Qb + (size_t)(b * S_ + qrow0 + l15) * 2048 + h * 128;
#pragma unroll
    for (int ds = 0; ds < 4; ds++) qf[ds] = *(const bf16x8*)(qp + ds * 32 + g * 8);
    // fused Q-RoPE (+ QSCALE fold): rotate (d, d+64) pairs in-register
    {
      const float2* tq = (const float2*)tab + (size_t)(qrow0 + l15) * 64 + g * 8;
#pragma unroll
      for (int ds = 0; ds < 2; ds++) {
        u16x8 a = __builtin_bit_cast(u16x8, qf[ds]);
        u16x8 bb = __builtin_bit_cast(u16x8, qf[ds + 2]);
#pragma unroll
        for (int j = 0; j < 8; j++) {
          float2 cs = tq[ds * 32 + j];  // freq idx = ds*32 + g*8 + j
          float c = cs.x * QSCALE, sn = cs.y * QSCALE;
          float lo = bf2f(a[j]), hi = bf2f(bb[j]);
          a[j] = f2bf(lo * c - hi * sn);
          bb[j] = f2bf(hi * c + lo * sn);
        }
        qf[ds] = __builtin_bit_cast(bf16x8, a);
        qf[ds + 2] = __builtin_bit_cast(bf16x8, bb);
      }
    }

    float m_r[4], l_r[4];
    f32x4 oa[8];
#pragma unroll
    for (int r = 0; r < 4; r++) { m_r[r] = -1e30f; l_r[r] = 0.f; }
#pragma unroll
    for (int n = 0; n < 8; n++) oa[n] = Z4;

    const int nt = qt + 1;
#pragma unroll
    for (int ro = 0; ro < 4; ++ro) {
      int c = ro * 256 + tid;
      int kv = c >> 4, p = c & 15;
      gl2lds16(Kbase + (size_t)kv * 1024 + 8 * (p ^ (kv & 15)), &Ks[0][ro * 2048 + w * 512]);
      int d = c >> 3, p2 = c & 7;
      gl2lds16(Vbase + (size_t)d * 2048 + 8 * (p2 ^ (d & 7)), &Vs[0][ro * 2048 + w * 512]);
    }
    __syncthreads();
    int cur = 0;

    for (int t = 0; t < nt; ++t) {
      const int kv0 = t * 64;
      if (t + 1 < nt) {
        const int nkv0 = kv0 + 64;
#pragma unroll
        for (int ro = 0; ro < 4; ++ro) {
          int c = ro * 256 + tid;
          int kv = c >> 4, p = c & 15;
          gl2lds16(Kbase + (size_t)(nkv0 + kv) * 1024 + 8 * (p ^ (kv & 15)),
                   &Ks[cur ^ 1][ro * 2048 + w * 512]);
          int d = c >> 3, p2 = c & 7;
          gl2lds16(Vbase + (size_t)d * 2048 + nkv0 + 8 * (p2 ^ (d & 7)),
                   &Vs[cur ^ 1][ro * 2048 + w * 512]);
        }
      }

      f32x4 sa[4];
#pragma unroll
      for (int c16 = 0; c16 < 4; c16++) sa[c16] = Z4;
      __builtin_amdgcn_s_setprio(1);
#pragma unroll
      for (int ds = 0; ds < 4; ++ds) {
#pragma unroll
        for (int c16 = 0; c16 < 4; ++c16) {
          bf16x8 kf = *(const bf16x8*)&Ks[cur][(c16 * 16 + l15) * 128 + ((ds * 4 + g) ^ l15) * 8];
          sa[c16] = mfma16(qf[ds], kf, sa[c16]);
        }
      }
      __builtin_amdgcn_s_setprio(0);

      if (kv0 + 63 > qrow0) {
#pragma unroll
        for (int c16 = 0; c16 < 4; c16++)
#pragma unroll
          for (int r = 0; r < 4; r++) {
            if (kv0 + c16 * 16 + l15 > qrow0 + g * 4 + r) sa[c16][r] = -1e30f;
          }
      }

      float lmax[4];
#pragma unroll
      for (int r = 0; r < 4; r++)
        lmax[r] = fmaxf(fmaxf(sa[0][r], sa[1][r]), fmaxf(sa[2][r], sa[3][r]));
      bool need = (lmax[0] > m_r[0] + 11.5415603f) || (lmax[1] > m_r[1] + 11.5415603f) ||
                  (lmax[2] > m_r[2] + 11.5415603f) || (lmax[3] > m_r[3] + 11.5415603f);
      if (__any(need)) {
        float pm[4];
#pragma unroll
        for (int r = 0; r < 4; r++) pm[r] = lmax[r];
#pragma unroll
        for (int off = 1; off < 16; off <<= 1)
#pragma unroll
          for (int r = 0; r < 4; r++) pm[r] = fmaxf(pm[r], __shfl_xor(pm[r], off));
#pragma unroll
        for (int r = 0; r < 4; r++) {
          float mn = fmaxf(m_r[r], pm[r]);
          float corr = exp2f(m_r[r] - mn);
          m_r[r] = mn;
          l_r[r] *= corr;
#pragma unroll
          for (int n = 0; n < 8; n++) oa[n][r] *= corr;
        }
      }

#pragma unroll
      for (int c16 = 0; c16 < 4; c16++)
#pragma unroll
        for (int r = 0; r < 4; r++)
          Ps[w][(g * 4 + r) * 72 + c16 * 16 + l15] =
              f2bf(exp2f(sa[c16][r] - m_r[r]));
      asm volatile("s_waitcnt lgkmcnt(0)" ::: "memory");
      __builtin_amdgcn_sched_barrier(0);

      f32x4 srow = Z4;
      __builtin_amdgcn_s_setprio(1);
#pragma unroll
      for (int ks = 0; ks < 2; ++ks) {
        bf16x8 pa = *(const bf16x8*)&Ps[w][l15 * 72 + ks * 32 + g * 8];
        srow = mfma16(pa, ones, srow);
#pragma unroll
        for (int n = 0; n < 8; n++) {
          bf16x8 vf = *(const bf16x8*)&Vs[cur][(n * 16 + l15) * 64 + (((ks * 4 + g) ^ (l15 & 7))) * 8];
          oa[n] = mfma16(pa, vf, oa[n]);
        }
      }
      __builtin_amdgcn_s_setprio(0);
#pragma unroll
      for (int r = 0; r < 4; r++) l_r[r] += srow[r];

      __syncthreads();
      cur ^= 1;
    }

    float inv[4];
#pragma unroll
    for (int r = 0; r < 4; r++) inv[r] = 1.0f / l_r[r];
#pragma unroll
    for (int n = 0; n < 8; n++)
#pragma unroll
      for (int r = 0; r < 4; r++) {
        size_t row = (size_t)b * S_ + qrow0 + g * 4 + r;
        Ob[row * 2048 + h * 128 + n * 16 + l15] = f2bf(oa[n][r] * inv[r]);
      }
  }
}

extern "C" void kernel_launch(void* const* d_in, const int* in_sizes, int n_in,
                              void* d_out, int out_size, void* d_ws, size_t ws_size,
                              hipStream_t stream) {
  const float* hid = (const float*)d_in[0];
  // d_in[1] = attention_mask: exactly causal; implemented directly in attn_kernel.
  const float* wq = (const float*)d_in[2];
  const float* wk = (const float*)d_in[3];
  const float* wv = (const float*)d_in[4];
  const float* wo = (const float*)d_in[5];
  float* out = (float*)d_out;
  char* ws = (char*)d_ws;

  // workspace layout (52 MB total)
  u16* hb     = (u16*)(ws);                   // 16MB: hidden bf16 -> later attn output
  u16* wqkvT  = (u16*)(ws + (16u << 20));     // 12MB: [wqT;wkT;wvT] (3072 x 2048)
  u16* Vt     = (u16*)(ws + (16u << 20));     //  4MB: reuse after QKV GEMM
  float* tab  = (float*)(ws + (20u << 20));   //  1MB: rope table, written AFTER QKV GEMM
  u16* woT    = (u16*)(ws + (20u << 20));     //  8MB: written AFTER attn (overwrites tab)
  u16* Qb     = (u16*)(ws + (28u << 20));     // 16MB
  u16* KVb    = (u16*)(ws + (44u << 20));     //  8MB

  // fused prologue: cvt(hidden) + weight transpose
  prologue<<<10240, 256, 0, stream>>>(hid, wq, wk, wv, hb, wqkvT);

  // fused QKV projection: [4096,2048] x [3072,2048]^T -> Qb | KVb
  gemm_bt1<<<768, 256, 0, stream>>>(hb, wqkvT, Qb, KVb, 4096, 3072, 2048);

  // fused midpass: rope table | K-RoPE (inline trig) | V transpose
  midpass<<<3072, 256, 0, stream>>>(KVb, Vt, tab);

  attn_kernel<<<dim3(16, 16, 2), 256, 0, stream>>>(Qb, KVb, Vt, tab, hb);

  // woT at ws+20M overwrites tab -- safe only after attn has run.
  transpose_f32_bf16<<<dim3(64, 64), 256, 0, stream>>>(wo, woT, 2048, 2048);

  gemm_o64<<<512, 256, 0, stream>>>(hb, woT, out);
}